// Round 12
// baseline (318.511 us; speedup 1.0000x reference)
//
#include <hip/hip_runtime.h>
#include <math.h>

#define SCAN_BLK 1024
#define BN_EPS 1e-5f

typedef __attribute__((ext_vector_type(8))) short short8;
typedef __attribute__((ext_vector_type(4))) short short4v;
typedef __attribute__((ext_vector_type(4))) float f32x4;

__device__ __forceinline__ float eluf(float x){ return x > 0.f ? x : (expf(x) - 1.f); }
__device__ __forceinline__ unsigned short f2bf(float f){
  unsigned u = __float_as_uint(f);
  u += 0x7FFFu + ((u >> 16) & 1u);          // RNE
  return (unsigned short)(u >> 16);
}
__device__ __forceinline__ float bf2f(unsigned short s){
  return __uint_as_float(((unsigned)s) << 16);
}
__device__ __forceinline__ unsigned fmap(float f){
  unsigned b = __float_as_uint(f);
  return (b & 0x80000000u) ? ~b : (b | 0x80000000u);
}
__device__ __forceinline__ float funmap(unsigned u){
  unsigned b = (u & 0x80000000u) ? (u ^ 0x80000000u) : ~u;
  return __uint_as_float(b);
}
__device__ __forceinline__ float lrelu(float a){ return a > 0.f ? a : 0.2f * a; }

// ---------------- CSR build ----------------
__global__ void k_count(const int* __restrict__ ei, int* __restrict__ deg, int ne, int e2)
{
  int t = blockIdx.x * 256 + threadIdx.x;
  if (t >= e2) return;
  int dst = (t < ne) ? ei[ne + t] : t - ne;
  atomicAdd(&deg[dst], 1);
}

__global__ void k_scan1(const int* __restrict__ deg, int* __restrict__ rowptr,
                        int* __restrict__ partials, int n)
{
  __shared__ int sh[SCAN_BLK];
  int t = threadIdx.x, base = blockIdx.x * SCAN_BLK;
  int v = (base + t < n) ? deg[base + t] : 0;
  sh[t] = v;
  __syncthreads();
  for (int off = 1; off < SCAN_BLK; off <<= 1) {
    int u = 0;
    if (t >= off) u = sh[t - off];
    __syncthreads();
    if (t >= off) sh[t] += u;
    __syncthreads();
  }
  if (base + t < n) rowptr[base + t] = sh[t] - v;   // exclusive
  if (t == SCAN_BLK - 1) partials[blockIdx.x] = sh[t];
}

__global__ void k_scan2(int* __restrict__ rowptr, const int* __restrict__ partials, int n)
{
  int base = blockIdx.x * SCAN_BLK;
  int add = 0;
  for (int i = 0; i < blockIdx.x; i++) add += partials[i];
  int t = threadIdx.x;
  if (base + t < n) rowptr[base + t] += add;
}

__global__ void k_fill(const int* __restrict__ ei, const int* __restrict__ rowptr,
                       int* __restrict__ cursor, int* __restrict__ col, int ne, int e2)
{
  int t = blockIdx.x * 256 + threadIdx.x;
  if (t >= e2) return;
  int src, dst;
  if (t < ne) { src = ei[t]; dst = ei[ne + t]; } else { src = dst = t - ne; }
  int pos = rowptr[dst] + atomicAdd(&cursor[dst], 1);
  col[pos] = src;
}

__global__ void k_dinv(const int* __restrict__ deg, float* __restrict__ dinv, int n)
{
  int t = blockIdx.x * 256 + threadIdx.x;
  if (t < n) dinv[t] = rsqrtf(fmaxf((float)deg[t], 1.f));
}

// ---------------- weight pack for MFMA B-fragments ----------------
__global__ void k_pack(const float* __restrict__ W, unsigned short* __restrict__ Wp,
                       int N, int nct)
{
  int tid = threadIdx.x;              // 512
  int l = tid >> 3, j = tid & 7;
  int ct = blockIdx.x >> 3, ks = blockIdx.x & 7;
  int k = ks * 32 + (l >> 4) * 8 + j;
  int c = ct * 16 + (l & 15);
  Wp[(size_t)(ks * nct + ct) * 512 + tid] = f2bf(W[(size_t)k * N + c]);
}

// ---------------- pack es/ed projection into one 16-col MFMA B tile ----------------
__global__ void k_pack_es(const float* __restrict__ WasT, unsigned short* __restrict__ Wes)
{
  int tid = threadIdx.x;              // 512
  int l = tid >> 3, j = tid & 7;
  int ks = blockIdx.x;                // 8
  int k = ks * 32 + (l >> 4) * 8 + j;
  int c = l & 15;
  float v = (c < 8) ? WasT[(size_t)c * 256 + k] : 0.f;
  Wes[(size_t)(ks * 64 + l) * 8 + j] = f2bf(v);
}

// ---------------- precompute: Ws1/Wd1[10][4] = W1 . a_{s,d}1 ----------------
__global__ void k_prep1(const float* __restrict__ W1, const float* __restrict__ as1,
                        const float* __restrict__ ad1,
                        float* __restrict__ Ws1, float* __restrict__ Wd1)
{
  int t = threadIdx.x;
  if (t >= 80) return;
  int half = t / 40, r = t % 40;
  int k = r / 4, h = r % 4;
  const float* a = half ? ad1 : as1;
  float s = 0.f;
  for (int c = 0; c < 64; c++) s += W1[k * 256 + h * 64 + c] * a[h * 64 + c];
  (half ? Wd1 : Ws1)[k * 4 + h] = s;
}

// ---------------- precompute: WasT[8][256]: rows 0-3 = W2.a_s2, 4-7 = W2.a_d2 --------
__global__ void k_prep2(const float* __restrict__ W2, const float* __restrict__ as2,
                        const float* __restrict__ ad2, float* __restrict__ WasT)
{
  int g = blockIdx.x * 256 + threadIdx.x;    // 0..2047
  if (g >= 2048) return;
  int half = g >= 1024, r = g & 1023;
  int i = r >> 2, h = r & 3;
  const float* a = half ? ad2 : as2;
  float s = 0.f;
  for (int c = 0; c < 64; c++) s += W2[(size_t)i * 256 + h * 64 + c] * a[h * 64 + c];
  WasT[(size_t)(half * 4 + h) * 256 + i] = s;
}

// ---------------- precompute fused BN scale/shift: y*A + B ----------------
__global__ void k_prep_bn(const float* __restrict__ bi1, const float* __restrict__ g1,
                          const float* __restrict__ b1, const float* __restrict__ m1,
                          const float* __restrict__ v1,
                          const float* __restrict__ bi2, const float* __restrict__ g2,
                          const float* __restrict__ b2, const float* __restrict__ m2,
                          const float* __restrict__ v2,
                          float* __restrict__ A1, float* __restrict__ B1,
                          float* __restrict__ A2, float* __restrict__ B2)
{
  int c = threadIdx.x;
  if (c < 256) {
    float a = rsqrtf(v1[c] + BN_EPS) * g1[c];
    A1[c] = a; B1[c] = (bi1[c] - m1[c]) * a + b1[c];
    a = rsqrtf(v2[c] + BN_EPS) * g2[c];
    A2[c] = a; B2[c] = (bi2[c] - m2[c]) * a + b2[c];
  }
}

// ---------------- es1/ed1 = x @ Ws1/Wd1 ----------------
__global__ void k_es1(const float* __restrict__ x, const float* __restrict__ Ws1,
                      const float* __restrict__ Wd1,
                      float* __restrict__ es, float* __restrict__ ed, int n)
{
  int t = blockIdx.x * 256 + threadIdx.x;
  if (t >= n) return;
  float xr[10];
  #pragma unroll
  for (int k = 0; k < 10; k++) xr[k] = x[(size_t)t * 10 + k];
  float e0[4] = {0,0,0,0}, e1[4] = {0,0,0,0};
  #pragma unroll
  for (int k = 0; k < 10; k++) {
    #pragma unroll
    for (int h = 0; h < 4; h++) {
      e0[h] += xr[k] * Ws1[k * 4 + h];
      e1[h] += xr[k] * Wd1[k * 4 + h];
    }
  }
  *(float4*)&es[t * 4] = make_float4(e0[0], e0[1], e0[2], e0[3]);
  *(float4*)&ed[t * 4] = make_float4(e1[0], e1[1], e1[2], e1[3]);
}

// ---------------- es2/ed2 via MFMA over slice-major actAs[8][n][32] ----------------
__global__ __launch_bounds__(256) void k_mfma_esed(
    const unsigned short* __restrict__ actAs, const unsigned short* __restrict__ Wes,
    float* __restrict__ es, float* __restrict__ ed, int n)
{
  int tid = threadIdx.x, wave = tid >> 6, lane = tid & 63;
  int l15 = lane & 15, lg = lane >> 4;
  int rbase = blockIdx.x * 64 + wave * 16;
  int arow = rbase + l15; if (arow > n - 1) arow = n - 1;

  f32x4 acc = {0.f, 0.f, 0.f, 0.f};
  #pragma unroll
  for (int ks = 0; ks < 8; ks++) {
    short8 a = *(const short8*)&actAs[(size_t)ks * n * 32 + (size_t)arow * 32 + lg * 8];
    short8 b = *(const short8*)&Wes[(size_t)(ks * 64 + lane) * 8];
    acc = __builtin_amdgcn_mfma_f32_16x16x32_bf16(a, b, acc, 0, 0, 0);
  }

  #pragma unroll
  for (int r = 0; r < 4; r++) {
    int row = rbase + lg * 4 + r;
    if (row < n) {
      if (l15 < 4)            es[row * 4 + l15] = acc[r];
      else if (l15 < 8)       ed[row * 4 + (l15 - 4)] = acc[r];
    }
  }
}

// ---------------- layer-1: fused online-softmax aggregate of raw x -> xa[N][4][10] ---
__global__ void k_xagg(const int* __restrict__ rowptr, const int* __restrict__ deg,
                       const int* __restrict__ col,
                       const float* __restrict__ es, const float* __restrict__ ed,
                       const float* __restrict__ x, float* __restrict__ xa, int n)
{
  int d = blockIdx.x * 4 + (threadIdx.x >> 6);
  if (d >= n) return;
  int lane = threadIdx.x & 63;
  int slot = lane >> 4, k = lane & 15;
  int start = rowptr[d], cnt = deg[d];
  bool active = (k < 10);
  float4 edv = *(const float4*)&ed[d * 4];

  float a0 = 0.f, a1 = 0.f, a2 = 0.f, a3 = 0.f;
  float s0 = 0.f, s1 = 0.f, s2 = 0.f, s3 = 0.f;
  int i = slot;
  for (; i + 4 < cnt; i += 8) {
    int e0 = start + i, e1 = start + i + 4;
    int sa = col[e0], sb = col[e1];
    float4 u0 = *(const float4*)&es[sa * 4];
    float4 u1 = *(const float4*)&es[sb * 4];
    float x0 = active ? x[(size_t)sa * 10 + k] : 0.f;
    float x1 = active ? x[(size_t)sb * 10 + k] : 0.f;
    float ex;
    ex = expf(lrelu(u0.x + edv.x)); a0 += ex * x0; s0 += ex;
    ex = expf(lrelu(u0.y + edv.y)); a1 += ex * x0; s1 += ex;
    ex = expf(lrelu(u0.z + edv.z)); a2 += ex * x0; s2 += ex;
    ex = expf(lrelu(u0.w + edv.w)); a3 += ex * x0; s3 += ex;
    ex = expf(lrelu(u1.x + edv.x)); a0 += ex * x1; s0 += ex;
    ex = expf(lrelu(u1.y + edv.y)); a1 += ex * x1; s1 += ex;
    ex = expf(lrelu(u1.z + edv.z)); a2 += ex * x1; s2 += ex;
    ex = expf(lrelu(u1.w + edv.w)); a3 += ex * x1; s3 += ex;
  }
  if (i < cnt) {
    int e0 = start + i;
    int sa = col[e0];
    float4 u0 = *(const float4*)&es[sa * 4];
    float x0 = active ? x[(size_t)sa * 10 + k] : 0.f;
    float ex;
    ex = expf(lrelu(u0.x + edv.x)); a0 += ex * x0; s0 += ex;
    ex = expf(lrelu(u0.y + edv.y)); a1 += ex * x0; s1 += ex;
    ex = expf(lrelu(u0.z + edv.z)); a2 += ex * x0; s2 += ex;
    ex = expf(lrelu(u0.w + edv.w)); a3 += ex * x0; s3 += ex;
  }
  a0 += __shfl_xor(a0, 16, 64); a0 += __shfl_xor(a0, 32, 64);
  a1 += __shfl_xor(a1, 16, 64); a1 += __shfl_xor(a1, 32, 64);
  a2 += __shfl_xor(a2, 16, 64); a2 += __shfl_xor(a2, 32, 64);
  a3 += __shfl_xor(a3, 16, 64); a3 += __shfl_xor(a3, 32, 64);
  s0 += __shfl_xor(s0, 16, 64); s0 += __shfl_xor(s0, 32, 64);
  s1 += __shfl_xor(s1, 16, 64); s1 += __shfl_xor(s1, 32, 64);
  s2 += __shfl_xor(s2, 16, 64); s2 += __shfl_xor(s2, 32, 64);
  s3 += __shfl_xor(s3, 16, 64); s3 += __shfl_xor(s3, 32, 64);

  if (slot == 0 && active) {
    float* xo = &xa[(size_t)d * 40];
    xo[k]      = a0 / (s0 + 1e-16f);
    xo[10 + k] = a1 / (s1 + 1e-16f);
    xo[20 + k] = a2 / (s2 + 1e-16f);
    xo[30 + k] = a3 / (s3 + 1e-16f);
  }
}

// ---------------- layer-1 GEMM: xa @ W1 + BN1 + ELU -> actAs slice-major ------------
__global__ void k_gemm_xa(const float* __restrict__ xa, const float* __restrict__ W1,
                          const float* __restrict__ A1, const float* __restrict__ B1,
                          unsigned short* __restrict__ actAs, int n)
{
  __shared__ float xal[160];
  int tid = threadIdx.x;
  int n0 = blockIdx.x * 4;
  if (tid < 160 && (size_t)n0 * 40 + tid < (size_t)n * 40)
    xal[tid] = xa[(size_t)n0 * 40 + tid];
  __syncthreads();
  int c = tid, h = c >> 6;
  int slice = c >> 5, cin = c & 31;
  float w[10];
  #pragma unroll
  for (int k = 0; k < 10; k++) w[k] = W1[k * 256 + c];
  float a1 = A1[c], b1 = B1[c];
  #pragma unroll
  for (int m = 0; m < 4; m++) {
    int nn = n0 + m;
    if (nn >= n) break;
    float acc = 0.f;
    #pragma unroll
    for (int k = 0; k < 10; k++) acc += xal[m * 40 + h * 10 + k] * w[k];
    actAs[(size_t)slice * n * 32 + (size_t)nn * 32 + cin] = f2bf(eluf(acc * a1 + b1));
  }
}

// ---------------- layer-2 gather, XCD-sliced: slice = blockIdx & 7 ----------------
// Each XCD's L2 caches one 3.2 MB slice of actAs. 8 dst-slots/wave x 8 lanes x 4 cols.
// Edges serial per slot: every lane sees all edges -> sex identical, no shuffles.
__global__ void k_gat_gather(const int* __restrict__ rowptr, const int* __restrict__ deg,
                             const int* __restrict__ col,
                             const float* __restrict__ es, const float* __restrict__ ed,
                             const unsigned short* __restrict__ actAs,
                             unsigned short* __restrict__ outb, int n)
{
  int slice = blockIdx.x & 7, grp = blockIdx.x >> 3;
  int wave = threadIdx.x >> 6, lane = threadIdx.x & 63;
  int slot = lane >> 3, c4 = (lane & 7) * 4;
  int d = grp * 32 + wave * 8 + slot;
  if (d >= n) return;
  int head = slice >> 1;
  int start = rowptr[d], cnt = deg[d];
  float edh = ed[d * 4 + head];
  const unsigned short* base = actAs + (size_t)slice * n * 32;

  float a0 = 0.f, a1 = 0.f, a2 = 0.f, a3 = 0.f, sex = 0.f;
  int i = 0;
  for (; i + 2 <= cnt; i += 2) {
    int s0 = col[start + i], s1 = col[start + i + 1];
    float x0 = expf(lrelu(es[s0 * 4 + head] + edh));
    float x1 = expf(lrelu(es[s1 * 4 + head] + edh));
    short4v h0 = *(const short4v*)&base[(size_t)s0 * 32 + c4];
    short4v h1 = *(const short4v*)&base[(size_t)s1 * 32 + c4];
    a0 += bf2f((unsigned short)h0[0]) * x0 + bf2f((unsigned short)h1[0]) * x1;
    a1 += bf2f((unsigned short)h0[1]) * x0 + bf2f((unsigned short)h1[1]) * x1;
    a2 += bf2f((unsigned short)h0[2]) * x0 + bf2f((unsigned short)h1[2]) * x1;
    a3 += bf2f((unsigned short)h0[3]) * x0 + bf2f((unsigned short)h1[3]) * x1;
    sex += x0 + x1;
  }
  if (i < cnt) {
    int s0 = col[start + i];
    float x0 = expf(lrelu(es[s0 * 4 + head] + edh));
    short4v h0 = *(const short4v*)&base[(size_t)s0 * 32 + c4];
    a0 += bf2f((unsigned short)h0[0]) * x0;
    a1 += bf2f((unsigned short)h0[1]) * x0;
    a2 += bf2f((unsigned short)h0[2]) * x0;
    a3 += bf2f((unsigned short)h0[3]) * x0;
    sex += x0;
  }
  float sv = 1.f / (sex + 1e-16f);
  short4v o;
  o[0] = (short)f2bf(a0 * sv);
  o[1] = (short)f2bf(a1 * sv);
  o[2] = (short)f2bf(a2 * sv);
  o[3] = (short)f2bf(a3 * sv);
  *(short4v*)&outb[(size_t)d * 256 + slice * 32 + c4] = o;
}

// ---------------- MFMA GEMM with LDS-staged B; optional fused BN+ELU epilogue ---------
template<int NCT, bool BNEPI>
__global__ __launch_bounds__(256) void k_mfma_gemm(
    const unsigned short* __restrict__ act, const unsigned short* __restrict__ Wp,
    unsigned short* __restrict__ outb,
    const float* __restrict__ Abn, const float* __restrict__ Bbn, int n)
{
  __shared__ unsigned short bsh[NCT * 512];
  int tid = threadIdx.x, wave = tid >> 6, lane = tid & 63;
  int l15 = lane & 15, lg = lane >> 4;
  int rbase = blockIdx.x * 64 + wave * 16;
  int arow = rbase + l15; if (arow > n - 1) arow = n - 1;
  const unsigned short* ap = &act[(size_t)arow * 256 + lg * 8];

  constexpr int NCH = (NCT >= 4) ? NCT / 4 : 1;
  f32x4 acc[NCT];
  f32x4 z = {0.f, 0.f, 0.f, 0.f};
  #pragma unroll
  for (int ct = 0; ct < NCT; ct++) acc[ct] = z;

  for (int ks = 0; ks < 8; ks++) {
    const unsigned short* src = Wp + (size_t)ks * NCT * 512 + wave * NCT * 128;
    short8 stg[NCH];
    #pragma unroll
    for (int c = 0; c < NCH; c++)
      stg[c] = *(const short8*)(src + c * 512 + lane * 8);
    short8 a = *(const short8*)(ap + ks * 32);
    __syncthreads();
    #pragma unroll
    for (int c = 0; c < NCH; c++)
      *(short8*)&bsh[wave * NCT * 128 + c * 512 + lane * 8] = stg[c];
    __syncthreads();
    #pragma unroll
    for (int ct = 0; ct < NCT; ct++) {
      short8 b = *(const short8*)&bsh[(ct * 64 + lane) * 8];
      acc[ct] = __builtin_amdgcn_mfma_f32_16x16x32_bf16(a, b, acc[ct], 0, 0, 0);
    }
  }

  float abn[NCT], bbn[NCT];
  if (BNEPI) {
    #pragma unroll
    for (int ct = 0; ct < NCT; ct++) {
      abn[ct] = Abn[ct * 16 + l15];
      bbn[ct] = Bbn[ct * 16 + l15];
    }
  }
  #pragma unroll
  for (int r = 0; r < 4; r++) {
    int row = rbase + lg * 4 + r;
    if (row < n) {
      #pragma unroll
      for (int ct = 0; ct < NCT; ct++) {
        float v = acc[ct][r];
        if (BNEPI) v = eluf(v * abn[ct] + bbn[ct]);
        outb[(size_t)row * (NCT * 16) + ct * 16 + l15] = f2bf(v);
      }
    }
  }
}

// ---------------- GCN gather: 8 slots, 2x unroll + BN/ELU -> fp32 hout ----------------
__global__ void k_gcn_gather(const int* __restrict__ rowptr, const int* __restrict__ deg,
                             const int* __restrict__ col, const float* __restrict__ dinv,
                             const unsigned short* __restrict__ xwb,
                             const float* __restrict__ bias,
                             const float* __restrict__ gg, const float* __restrict__ bb,
                             const float* __restrict__ mm, const float* __restrict__ vv,
                             float* __restrict__ hout, int n)
{
  int d = blockIdx.x * 4 + (threadIdx.x >> 6);
  if (d >= n) return;
  int lane = threadIdx.x & 63;
  int slot = lane >> 3, cg = (lane & 7) * 8;
  int start = rowptr[d], cnt = deg[d];
  float dinvd = rsqrtf(fmaxf((float)cnt, 1.f));

  float acc[8] = {0.f,0.f,0.f,0.f,0.f,0.f,0.f,0.f};
  int i = slot;
  for (; i + 8 < cnt; i += 16) {
    int s0 = col[start + i], s1 = col[start + i + 8];
    float n0 = dinv[s0], n1 = dinv[s1];
    short8 h0 = *(const short8*)&xwb[(size_t)s0 * 64 + cg];
    short8 h1 = *(const short8*)&xwb[(size_t)s1 * 64 + cg];
    #pragma unroll
    for (int j = 0; j < 8; j++)
      acc[j] += bf2f((unsigned short)h0[j]) * n0 + bf2f((unsigned short)h1[j]) * n1;
  }
  if (i < cnt) {
    int s0 = col[start + i];
    float n0 = dinv[s0];
    short8 h0 = *(const short8*)&xwb[(size_t)s0 * 64 + cg];
    #pragma unroll
    for (int j = 0; j < 8; j++)
      acc[j] += bf2f((unsigned short)h0[j]) * n0;
  }
  #pragma unroll
  for (int j = 0; j < 8; j++) {
    acc[j] += __shfl_xor(acc[j], 8, 64);
    acc[j] += __shfl_xor(acc[j], 16, 64);
    acc[j] += __shfl_xor(acc[j], 32, 64);
    acc[j] *= dinvd;
  }

  if (lane < 8) {
    float out[8];
    #pragma unroll
    for (int j = 0; j < 8; j++) {
      int c = cg + j;
      float r = ((acc[j] + bias[c]) - mm[c]) * rsqrtf(vv[c] + BN_EPS) * gg[c] + bb[c];
      out[j] = eluf(r);
    }
    *(float4*)&hout[(size_t)d * 64 + cg]     = make_float4(out[0], out[1], out[2], out[3]);
    *(float4*)&hout[(size_t)d * 64 + cg + 4] = make_float4(out[4], out[5], out[6], out[7]);
  }
}

// ---------------- pooling: per-wave run accumulation, rare flushes ----------------
__global__ void k_pool_partial(const float* __restrict__ hout, const int* __restrict__ batch,
                               float* __restrict__ psum, unsigned* __restrict__ pmaxu,
                               int n)
{
  int wave = threadIdx.x >> 6, lane = threadIdx.x & 63;
  int wbase = blockIdx.x * 128 + wave * 32;
  int wend = wbase + 32; if (wend > n) wend = n;
  if (wbase >= n) return;

  int g_cur = -1;
  float s = 0.f, mx = -1e30f;
  for (int node = wbase; node < wend; node++) {
    int g = batch[node];
    if (g != g_cur) {
      if (g_cur >= 0) {
        atomicAdd(&psum[g_cur * 64 + lane], s);
        atomicMax(&pmaxu[g_cur * 64 + lane], fmap(mx));
      }
      g_cur = g; s = 0.f; mx = -1e30f;
    }
    float v = hout[(size_t)node * 64 + lane];
    s += v;
    mx = fmaxf(mx, v);
  }
  if (g_cur >= 0) {
    atomicAdd(&psum[g_cur * 64 + lane], s);
    atomicMax(&pmaxu[g_cur * 64 + lane], fmap(mx));
  }
}

// ---------------- heads: one block (64 thr) per graph ----------------
__global__ void k_heads(const float* __restrict__ psum, const unsigned* __restrict__ pmaxu,
                        const int* __restrict__ batch,
                        const float* __restrict__ Wr, const float* __restrict__ br,
                        const float* __restrict__ Wh1, const float* __restrict__ bh1,
                        const float* __restrict__ Wh2, const float* __restrict__ bh2,
                        const float* __restrict__ Wh3, const float* __restrict__ bh3,
                        const float* __restrict__ Wl1, const float* __restrict__ bl1,
                        const float* __restrict__ Wl2, const float* __restrict__ bl2,
                        const float* __restrict__ We1, const float* __restrict__ be1,
                        const float* __restrict__ We2, const float* __restrict__ be2,
                        float* __restrict__ outp, int n, int xg_off)
{
  __shared__ float cat[128], xg[64], t1[32], t2[16], l1[32], e1[16];
  int g = blockIdx.x, c = threadIdx.x;  // 64 threads

  int lo = 0, hi = n;
  while (lo < hi) { int mid = (lo + hi) >> 1; if (batch[mid] < g) lo = mid + 1; else hi = mid; }
  int start = lo;
  lo = start; hi = n;
  while (lo < hi) { int mid = (lo + hi) >> 1; if (batch[mid] < g + 1) lo = mid + 1; else hi = mid; }
  int cntg = lo - start;

  float mean = psum[g * 64 + c] / fmaxf((float)cntg, 1.f);
  float mxv = (cntg > 0) ? funmap(pmaxu[g * 64 + c]) : 0.f;
  cat[c] = mean; cat[64 + c] = mxv;
  __syncthreads();
  float a = br[c];
  for (int i = 0; i < 128; i++) a += cat[i] * Wr[i * 64 + c];
  xg[c] = a;
  outp[xg_off + g * 64 + c] = a;
  __syncthreads();
  if (c < 32) {
    float u = bh1[c]; for (int i = 0; i < 64; i++) u += xg[i] * Wh1[i * 32 + c];
    t1[c] = fmaxf(u, 0.f);
    float v = bl1[c]; for (int i = 0; i < 64; i++) v += xg[i] * Wl1[i * 32 + c];
    l1[c] = fmaxf(v, 0.f);
  }
  __syncthreads();
  if (c < 16) {
    float u = bh2[c]; for (int i = 0; i < 32; i++) u += t1[i] * Wh2[i * 16 + c];
    t2[c] = fmaxf(u, 0.f);
    float v = be1[c]; for (int i = 0; i < 64; i++) v += xg[i] * We1[i * 16 + c];
    e1[c] = fmaxf(v, 0.f);
  }
  __syncthreads();
  if (c < 8) {
    float v = bl2[c]; for (int i = 0; i < 32; i++) v += l1[i] * Wl2[i * 8 + c];
    outp[64 + g * 8 + c] = v;
  }
  if (c == 0) {
    float u = bh3[0]; for (int i = 0; i < 16; i++) u += t2[i] * Wh3[i];
    outp[g] = 100.f / (1.f + expf(-u));
    float v = be2[0]; for (int i = 0; i < 16; i++) v += e1[i] * We2[i];
    outp[576 + g] = v;
  }
}

extern "C" void kernel_launch(void* const* d_in, const int* in_sizes, int n_in,
                              void* d_out, int out_size, void* d_ws, size_t ws_size,
                              hipStream_t stream)
{
  const float* x    = (const float*)d_in[0];
  const int*   ei   = (const int*)d_in[1];
  const int*   batch= (const int*)d_in[2];
  const float* W1   = (const float*)d_in[3];
  const float* as1  = (const float*)d_in[4];
  const float* ad1  = (const float*)d_in[5];
  const float* bi1  = (const float*)d_in[6];
  const float* W2   = (const float*)d_in[7];
  const float* as2  = (const float*)d_in[8];
  const float* ad2  = (const float*)d_in[9];
  const float* bi2  = (const float*)d_in[10];
  const float* bn1g = (const float*)d_in[11];
  const float* bn1b = (const float*)d_in[12];
  const float* bn1m = (const float*)d_in[13];
  const float* bn1v = (const float*)d_in[14];
  const float* bn2g = (const float*)d_in[15];
  const float* bn2b = (const float*)d_in[16];
  const float* bn2m = (const float*)d_in[17];
  const float* bn2v = (const float*)d_in[18];
  const float* bn3g = (const float*)d_in[19];
  const float* bn3b = (const float*)d_in[20];
  const float* bn3m = (const float*)d_in[21];
  const float* bn3v = (const float*)d_in[22];
  const float* Wg   = (const float*)d_in[23];
  const float* bg   = (const float*)d_in[24];
  const float* Wr   = (const float*)d_in[25];
  const float* br   = (const float*)d_in[26];
  const float* Wh1  = (const float*)d_in[27];
  const float* bh1  = (const float*)d_in[28];
  const float* Wh2  = (const float*)d_in[29];
  const float* bh2  = (const float*)d_in[30];
  const float* Wh3  = (const float*)d_in[31];
  const float* bh3  = (const float*)d_in[32];
  const float* Wl1  = (const float*)d_in[33];
  const float* bl1  = (const float*)d_in[34];
  const float* Wl2  = (const float*)d_in[35];
  const float* bl2  = (const float*)d_in[36];
  const float* We1  = (const float*)d_in[37];
  const float* be1  = (const float*)d_in[38];
  const float* We2  = (const float*)d_in[39];
  const float* be2  = (const float*)d_in[40];

  const int n  = in_sizes[2];         // 50000 nodes
  const int ne = in_sizes[1] / 2;     // 500000 edges
  const int e2 = ne + n;              // with self-loops

  float* ws = (float*)d_ws;
  size_t off = 0;
  unsigned short* bufA = (unsigned short*)(ws + off); off += (size_t)n * 128; // actAs / actB
  unsigned short* bufB = (unsigned short*)(ws + off); off += (size_t)n * 128; // agg2 / xwb
  float* xa   = ws + off; off += (size_t)n * 40;
  float* es   = ws + off; off += (size_t)n * 4;
  float* ed   = ws + off; off += (size_t)n * 4;
  float* dinv = ws + off; off += (size_t)n;
  int* rowptr = (int*)(ws + off); off += (size_t)n + 1;
  int* deg    = (int*)(ws + off); off += (size_t)n;
  int* cursor = (int*)(ws + off); off += (size_t)n;
  int* col    = (int*)(ws + off); off += (size_t)e2;
  int* partials = (int*)(ws + off); off += 64;
  unsigned short* Wp2 = (unsigned short*)(ws + off); off += 32768;  // 65536 bf16
  unsigned short* Wpg = (unsigned short*)(ws + off); off += 8192;   // 16384 bf16
  unsigned short* Wes = (unsigned short*)(ws + off); off += 2048;   // 4096 bf16
  float* Ws1  = ws + off; off += 40;
  float* Wd1  = ws + off; off += 40;
  float* WasT = ws + off; off += 2048;
  float* A1   = ws + off; off += 256;
  float* B1   = ws + off; off += 256;
  float* A2   = ws + off; off += 256;
  float* B2   = ws + off; off += 256;
  float* psum = ws + off; off += 64 * 64;
  unsigned* pmaxu = (unsigned*)(ws + off); off += 64 * 64;

  unsigned short* actAs = bufA;  // slice-major [8][n][32]
  unsigned short* agg2  = bufB;  // row-major [n][256]
  unsigned short* actB  = bufA;  // actAs dead after gather + esed
  unsigned short* xwb   = bufB;  // agg2 dead after layer-2 GEMM

  float* outp = (float*)d_out;
  float* hout = outp + 640;            // node embeddings region
  const int xg_off = 640 + n * 64;

  const int eb   = (e2 + 255) / 256;
  const int gb1  = (n + 3) / 4;
  const int gmb  = (n + 63) / 64;
  const int nsb  = (n + SCAN_BLK - 1) / SCAN_BLK;
  const int gsl  = 8 * ((n + 31) / 32);    // sliced gather grid

  // ---------- CSR build + precomputes ----------
  hipMemsetAsync(deg, 0, (size_t)n * sizeof(int), stream);
  hipMemsetAsync(cursor, 0, (size_t)n * sizeof(int), stream);
  k_count<<<eb, 256, 0, stream>>>(ei, deg, ne, e2);
  k_scan1<<<nsb, SCAN_BLK, 0, stream>>>(deg, rowptr, partials, n);
  k_scan2<<<nsb, SCAN_BLK, 0, stream>>>(rowptr, partials, n);
  k_fill<<<eb, 256, 0, stream>>>(ei, rowptr, cursor, col, ne, e2);
  k_dinv<<<(n + 255) / 256, 256, 0, stream>>>(deg, dinv, n);
  k_pack<<<128, 512, 0, stream>>>(W2, Wp2, 256, 16);
  k_pack<<<32, 512, 0, stream>>>(Wg, Wpg, 64, 4);
  k_prep1<<<1, 128, 0, stream>>>(W1, as1, ad1, Ws1, Wd1);
  k_prep2<<<8, 256, 0, stream>>>(W2, as2, ad2, WasT);
  k_pack_es<<<8, 512, 0, stream>>>(WasT, Wes);
  k_prep_bn<<<1, 256, 0, stream>>>(bi1, bn1g, bn1b, bn1m, bn1v,
                                   bi2, bn2g, bn2b, bn2m, bn2v,
                                   A1, B1, A2, B2);

  // ---------- GAT layer 1 (aggregate-first, fused softmax) ----------
  k_es1<<<(n + 255) / 256, 256, 0, stream>>>(x, Ws1, Wd1, es, ed, n);
  k_xagg<<<gb1, 256, 0, stream>>>(rowptr, deg, col, es, ed, x, xa, n);
  k_gemm_xa<<<gb1, 256, 0, stream>>>(xa, W1, A1, B1, actAs, n);

  // ---------- GAT layer 2 (aggregate-first, fused softmax, XCD-sliced gather) -------
  k_mfma_esed<<<gmb, 256, 0, stream>>>(actAs, Wes, es, ed, n);
  k_gat_gather<<<gsl, 256, 0, stream>>>(rowptr, deg, col, es, ed, actAs, agg2, n);
  k_mfma_gemm<16, true><<<gmb, 256, 0, stream>>>(agg2, Wp2, actB, A2, B2, n);

  // ---------- GCN ----------
  k_mfma_gemm<4, false><<<gmb, 256, 0, stream>>>(actB, Wpg, xwb, nullptr, nullptr, n);
  k_gcn_gather<<<gb1, 256, 0, stream>>>(rowptr, deg, col, dinv, xwb,
                                        bg, bn3g, bn3b, bn3m, bn3v, hout, n);

  // ---------- pooling + heads ----------
  hipMemsetAsync(psum, 0, 64 * 64 * sizeof(float), stream);
  hipMemsetAsync(pmaxu, 0, 64 * 64 * sizeof(unsigned), stream);
  k_pool_partial<<<(n + 127) / 128, 256, 0, stream>>>(hout, batch, psum, pmaxu, n);
  k_heads<<<64, 64, 0, stream>>>(psum, pmaxu, batch, Wr, br,
                                 Wh1, bh1, Wh2, bh2, Wh3, bh3,
                                 Wl1, bl1, Wl2, bl2, We1, be1, We2, be2,
                                 outp, n, xg_off);
}

// Round 13
// 287.955 us; speedup vs baseline: 1.1061x; 1.1061x over previous
//
#include <hip/hip_runtime.h>
#include <math.h>

#define SCAN_BLK 1024
#define BN_EPS 1e-5f

typedef __attribute__((ext_vector_type(8))) short short8;
typedef __attribute__((ext_vector_type(4))) short short4v;
typedef __attribute__((ext_vector_type(4))) float f32x4;

__device__ __forceinline__ float eluf(float x){ return x > 0.f ? x : (expf(x) - 1.f); }
__device__ __forceinline__ unsigned short f2bf(float f){
  unsigned u = __float_as_uint(f);
  u += 0x7FFFu + ((u >> 16) & 1u);          // RNE
  return (unsigned short)(u >> 16);
}
__device__ __forceinline__ float bf2f(unsigned short s){
  return __uint_as_float(((unsigned)s) << 16);
}
__device__ __forceinline__ unsigned fmap(float f){
  unsigned b = __float_as_uint(f);
  return (b & 0x80000000u) ? ~b : (b | 0x80000000u);
}
__device__ __forceinline__ float funmap(unsigned u){
  unsigned b = (u & 0x80000000u) ? (u ^ 0x80000000u) : ~u;
  return __uint_as_float(b);
}
__device__ __forceinline__ float lrelu(float a){ return a > 0.f ? a : 0.2f * a; }

// ---------------- CSR build ----------------
__global__ void k_count(const int* __restrict__ ei, int* __restrict__ deg, int ne, int e2)
{
  int t = blockIdx.x * 256 + threadIdx.x;
  if (t >= e2) return;
  int dst = (t < ne) ? ei[ne + t] : t - ne;
  atomicAdd(&deg[dst], 1);
}

// scan + dinv fused (deg value already in hand)
__global__ void k_scan1(const int* __restrict__ deg, int* __restrict__ rowptr,
                        int* __restrict__ partials, float* __restrict__ dinv, int n)
{
  __shared__ int sh[SCAN_BLK];
  int t = threadIdx.x, base = blockIdx.x * SCAN_BLK;
  int v = (base + t < n) ? deg[base + t] : 0;
  sh[t] = v;
  __syncthreads();
  for (int off = 1; off < SCAN_BLK; off <<= 1) {
    int u = 0;
    if (t >= off) u = sh[t - off];
    __syncthreads();
    if (t >= off) sh[t] += u;
    __syncthreads();
  }
  if (base + t < n) {
    rowptr[base + t] = sh[t] - v;   // exclusive
    dinv[base + t] = rsqrtf(fmaxf((float)v, 1.f));
  }
  if (t == SCAN_BLK - 1) partials[blockIdx.x] = sh[t];
}

__global__ void k_scan2(int* __restrict__ rowptr, const int* __restrict__ partials, int n)
{
  int base = blockIdx.x * SCAN_BLK;
  int add = 0;
  for (int i = 0; i < blockIdx.x; i++) add += partials[i];
  int t = threadIdx.x;
  if (base + t < n) rowptr[base + t] += add;
}

__global__ void k_fill(const int* __restrict__ ei, const int* __restrict__ rowptr,
                       int* __restrict__ cursor, int* __restrict__ col, int ne, int e2)
{
  int t = blockIdx.x * 256 + threadIdx.x;
  if (t >= e2) return;
  int src, dst;
  if (t < ne) { src = ei[t]; dst = ei[ne + t]; } else { src = dst = t - ne; }
  int pos = rowptr[dst] + atomicAdd(&cursor[dst], 1);
  col[pos] = src;
}

// ---------------- weight pack for MFMA B-fragments ----------------
__global__ void k_pack(const float* __restrict__ W, unsigned short* __restrict__ Wp,
                       int N, int nct)
{
  int tid = threadIdx.x;              // 512
  int l = tid >> 3, j = tid & 7;
  int ct = blockIdx.x >> 3, ks = blockIdx.x & 7;
  int k = ks * 32 + (l >> 4) * 8 + j;
  int c = ct * 16 + (l & 15);
  Wp[(size_t)(ks * nct + ct) * 512 + tid] = f2bf(W[(size_t)k * N + c]);
}

// ---------------- merged precompute: prep2 (blocks 0-7), prep1 + prep_bn (block 8) ---
__global__ void k_prep_all(const float* __restrict__ W1, const float* __restrict__ as1,
                           const float* __restrict__ ad1,
                           const float* __restrict__ W2, const float* __restrict__ as2,
                           const float* __restrict__ ad2,
                           const float* __restrict__ bi1, const float* __restrict__ g1,
                           const float* __restrict__ b1, const float* __restrict__ m1,
                           const float* __restrict__ v1,
                           const float* __restrict__ bi2, const float* __restrict__ g2,
                           const float* __restrict__ b2, const float* __restrict__ m2,
                           const float* __restrict__ v2,
                           float* __restrict__ Ws1, float* __restrict__ Wd1,
                           float* __restrict__ WasT,
                           float* __restrict__ A1, float* __restrict__ B1,
                           float* __restrict__ A2, float* __restrict__ B2)
{
  int t = threadIdx.x;
  if (blockIdx.x < 8) {
    int g = blockIdx.x * 256 + t;            // 0..2047
    int half = g >= 1024, r = g & 1023;
    int i = r >> 2, h = r & 3;
    const float* a = half ? ad2 : as2;
    float s = 0.f;
    for (int c = 0; c < 64; c++) s += W2[(size_t)i * 256 + h * 64 + c] * a[h * 64 + c];
    WasT[(size_t)(half * 4 + h) * 256 + i] = s;
  } else {
    if (t < 80) {
      int half = t / 40, r = t % 40;
      int k = r / 4, h = r % 4;
      const float* a = half ? ad1 : as1;
      float s = 0.f;
      for (int c = 0; c < 64; c++) s += W1[k * 256 + h * 64 + c] * a[h * 64 + c];
      (half ? Wd1 : Ws1)[k * 4 + h] = s;
    }
    if (t < 256) {
      float a = rsqrtf(v1[t] + BN_EPS) * g1[t];
      A1[t] = a; B1[t] = (bi1[t] - m1[t]) * a + b1[t];
      a = rsqrtf(v2[t] + BN_EPS) * g2[t];
      A2[t] = a; B2[t] = (bi2[t] - m2[t]) * a + b2[t];
    }
  }
}

// ---------------- es1/ed1 = x @ Ws1/Wd1 ----------------
__global__ void k_es1(const float* __restrict__ x, const float* __restrict__ Ws1,
                      const float* __restrict__ Wd1,
                      float* __restrict__ es, float* __restrict__ ed, int n)
{
  int t = blockIdx.x * 256 + threadIdx.x;
  if (t >= n) return;
  float xr[10];
  #pragma unroll
  for (int k = 0; k < 10; k++) xr[k] = x[(size_t)t * 10 + k];
  float e0[4] = {0,0,0,0}, e1[4] = {0,0,0,0};
  #pragma unroll
  for (int k = 0; k < 10; k++) {
    #pragma unroll
    for (int h = 0; h < 4; h++) {
      e0[h] += xr[k] * Ws1[k * 4 + h];
      e1[h] += xr[k] * Wd1[k * 4 + h];
    }
  }
  *(float4*)&es[t * 4] = make_float4(e0[0], e0[1], e0[2], e0[3]);
  *(float4*)&ed[t * 4] = make_float4(e1[0], e1[1], e1[2], e1[3]);
}

// ---------------- layer-1: fused online-softmax aggregate of raw x -> xa[N][4][10] ---
__global__ void k_xagg(const int* __restrict__ rowptr, const int* __restrict__ deg,
                       const int* __restrict__ col,
                       const float* __restrict__ es, const float* __restrict__ ed,
                       const float* __restrict__ x, float* __restrict__ xa, int n)
{
  int d = blockIdx.x * 4 + (threadIdx.x >> 6);
  if (d >= n) return;
  int lane = threadIdx.x & 63;
  int slot = lane >> 4, k = lane & 15;
  int start = rowptr[d], cnt = deg[d];
  bool active = (k < 10);
  float4 edv = *(const float4*)&ed[d * 4];

  float a0 = 0.f, a1 = 0.f, a2 = 0.f, a3 = 0.f;
  float s0 = 0.f, s1 = 0.f, s2 = 0.f, s3 = 0.f;
  int i = slot;
  for (; i + 4 < cnt; i += 8) {
    int e0 = start + i, e1 = start + i + 4;
    int sa = col[e0], sb = col[e1];
    float4 u0 = *(const float4*)&es[sa * 4];
    float4 u1 = *(const float4*)&es[sb * 4];
    float x0 = active ? x[(size_t)sa * 10 + k] : 0.f;
    float x1 = active ? x[(size_t)sb * 10 + k] : 0.f;
    float ex;
    ex = expf(lrelu(u0.x + edv.x)); a0 += ex * x0; s0 += ex;
    ex = expf(lrelu(u0.y + edv.y)); a1 += ex * x0; s1 += ex;
    ex = expf(lrelu(u0.z + edv.z)); a2 += ex * x0; s2 += ex;
    ex = expf(lrelu(u0.w + edv.w)); a3 += ex * x0; s3 += ex;
    ex = expf(lrelu(u1.x + edv.x)); a0 += ex * x1; s0 += ex;
    ex = expf(lrelu(u1.y + edv.y)); a1 += ex * x1; s1 += ex;
    ex = expf(lrelu(u1.z + edv.z)); a2 += ex * x1; s2 += ex;
    ex = expf(lrelu(u1.w + edv.w)); a3 += ex * x1; s3 += ex;
  }
  if (i < cnt) {
    int e0 = start + i;
    int sa = col[e0];
    float4 u0 = *(const float4*)&es[sa * 4];
    float x0 = active ? x[(size_t)sa * 10 + k] : 0.f;
    float ex;
    ex = expf(lrelu(u0.x + edv.x)); a0 += ex * x0; s0 += ex;
    ex = expf(lrelu(u0.y + edv.y)); a1 += ex * x0; s1 += ex;
    ex = expf(lrelu(u0.z + edv.z)); a2 += ex * x0; s2 += ex;
    ex = expf(lrelu(u0.w + edv.w)); a3 += ex * x0; s3 += ex;
  }
  a0 += __shfl_xor(a0, 16, 64); a0 += __shfl_xor(a0, 32, 64);
  a1 += __shfl_xor(a1, 16, 64); a1 += __shfl_xor(a1, 32, 64);
  a2 += __shfl_xor(a2, 16, 64); a2 += __shfl_xor(a2, 32, 64);
  a3 += __shfl_xor(a3, 16, 64); a3 += __shfl_xor(a3, 32, 64);
  s0 += __shfl_xor(s0, 16, 64); s0 += __shfl_xor(s0, 32, 64);
  s1 += __shfl_xor(s1, 16, 64); s1 += __shfl_xor(s1, 32, 64);
  s2 += __shfl_xor(s2, 16, 64); s2 += __shfl_xor(s2, 32, 64);
  s3 += __shfl_xor(s3, 16, 64); s3 += __shfl_xor(s3, 32, 64);

  if (slot == 0 && active) {
    float* xo = &xa[(size_t)d * 40];
    xo[k]      = a0 / (s0 + 1e-16f);
    xo[10 + k] = a1 / (s1 + 1e-16f);
    xo[20 + k] = a2 / (s2 + 1e-16f);
    xo[30 + k] = a3 / (s3 + 1e-16f);
  }
}

// ---------------- layer-1 GEMM + BN1 + ELU -> actA, with fused es2/ed2 epilogue ------
__global__ void k_gemm_xa(const float* __restrict__ xa, const float* __restrict__ W1,
                          const float* __restrict__ A1, const float* __restrict__ B1,
                          const float* __restrict__ WasT,
                          unsigned short* __restrict__ actA,
                          float* __restrict__ es, float* __restrict__ ed, int n)
{
  __shared__ float xal[160];
  __shared__ float actl[4][256];
  int tid = threadIdx.x;
  int n0 = blockIdx.x * 4;
  if (tid < 160 && (size_t)n0 * 40 + tid < (size_t)n * 40)
    xal[tid] = xa[(size_t)n0 * 40 + tid];
  __syncthreads();
  int c = tid, h = c >> 6;
  float w[10];
  #pragma unroll
  for (int k = 0; k < 10; k++) w[k] = W1[k * 256 + c];
  float a1 = A1[c], b1 = B1[c];
  #pragma unroll
  for (int m = 0; m < 4; m++) {
    int nn = n0 + m;
    if (nn >= n) break;
    float acc = 0.f;
    #pragma unroll
    for (int k = 0; k < 10; k++) acc += xal[m * 40 + h * 10 + k] * w[k];
    float v = eluf(acc * a1 + b1);
    actl[m][c] = v;
    actA[(size_t)nn * 256 + c] = f2bf(v);
  }
  __syncthreads();
  // es2/ed2: wave per node; lane owns 4 channels; 8 projections
  int wave = tid >> 6, lane = tid & 63;
  int nn = n0 + wave;
  if (nn < n) {
    float e[8] = {0,0,0,0,0,0,0,0};
    int c0 = lane * 4;
    #pragma unroll
    for (int j = 0; j < 4; j++) {
      float av = actl[wave][c0 + j];
      #pragma unroll
      for (int q = 0; q < 8; q++) e[q] += av * WasT[q * 256 + c0 + j];
    }
    #pragma unroll
    for (int off = 1; off < 64; off <<= 1) {
      #pragma unroll
      for (int q = 0; q < 8; q++) e[q] += __shfl_xor(e[q], off, 64);
    }
    if (lane == 0) {
      *(float4*)&es[nn * 4] = make_float4(e[0], e[1], e[2], e[3]);
      *(float4*)&ed[nn * 4] = make_float4(e[4], e[5], e[6], e[7]);
    }
  }
}

// ---------------- layer-2 gather: fused online softmax, 4x unroll (round-11 form) ----
__global__ void k_gat_gather(const int* __restrict__ rowptr, const int* __restrict__ deg,
                             const int* __restrict__ col,
                             const float* __restrict__ es, const float* __restrict__ ed,
                             const unsigned short* __restrict__ act,
                             unsigned short* __restrict__ outb, int n)
{
  int d = blockIdx.x * 4 + (threadIdx.x >> 6);
  if (d >= n) return;
  int lane = threadIdx.x & 63;
  int half = lane >> 5, l32 = lane & 31;
  int c8 = l32 * 8, head = l32 >> 3;
  int start = rowptr[d], cnt = deg[d];
  float edh = ed[d * 4 + head];

  float acc[8] = {0.f,0.f,0.f,0.f,0.f,0.f,0.f,0.f};
  float sex = 0.f;
  int T = (cnt > half) ? ((cnt - half + 1) >> 1) : 0;
  int ebase = start + half;
  int t = 0;
  for (; t + 4 <= T; t += 4) {
    int e0 = ebase + 2 * t, e1 = e0 + 2, e2 = e0 + 4, e3 = e0 + 6;
    int s0 = col[e0], s1 = col[e1], s2 = col[e2], s3 = col[e3];
    float x0 = expf(lrelu(es[s0 * 4 + head] + edh));
    float x1 = expf(lrelu(es[s1 * 4 + head] + edh));
    float x2 = expf(lrelu(es[s2 * 4 + head] + edh));
    float x3 = expf(lrelu(es[s3 * 4 + head] + edh));
    short8 h0 = *(const short8*)&act[(size_t)s0 * 256 + c8];
    short8 h1 = *(const short8*)&act[(size_t)s1 * 256 + c8];
    short8 h2 = *(const short8*)&act[(size_t)s2 * 256 + c8];
    short8 h3 = *(const short8*)&act[(size_t)s3 * 256 + c8];
    #pragma unroll
    for (int j = 0; j < 8; j++) {
      acc[j] += bf2f((unsigned short)h0[j]) * x0 + bf2f((unsigned short)h1[j]) * x1
              + bf2f((unsigned short)h2[j]) * x2 + bf2f((unsigned short)h3[j]) * x3;
    }
    sex += x0 + x1 + x2 + x3;
  }
  for (; t < T; t++) {
    int e0 = ebase + 2 * t;
    int s0 = col[e0];
    float x0 = expf(lrelu(es[s0 * 4 + head] + edh));
    short8 h0 = *(const short8*)&act[(size_t)s0 * 256 + c8];
    #pragma unroll
    for (int j = 0; j < 8; j++) acc[j] += bf2f((unsigned short)h0[j]) * x0;
    sex += x0;
  }
  #pragma unroll
  for (int j = 0; j < 8; j++)
    acc[j] += __shfl_xor(acc[j], 32, 64);
  sex += __shfl_xor(sex, 32, 64);

  if (half == 0) {
    float sv = 1.f / (sex + 1e-16f);
    short8 o;
    #pragma unroll
    for (int j = 0; j < 8; j++) o[j] = (short)f2bf(acc[j] * sv);
    *(short8*)&outb[(size_t)d * 256 + c8] = o;
  }
}

// ---------------- fused double GEMM: agg2 @ W2 (+BN2+ELU) -> LDS -> @ Wg -> xwb ------
// Stage 1: 256x256 MFMA GEMM with LDS-staged B, BN+ELU epilogue into padded LDS tile.
// Stage 2: 256x64 MFMA GEMM reading the LDS tile (row stride 264 avoids conflicts),
//          B loaded per-wave from global (8 KB, L1-resident).
__global__ __launch_bounds__(256) void k_mfma_gemm2(
    const unsigned short* __restrict__ agg2, const unsigned short* __restrict__ Wp2,
    const unsigned short* __restrict__ Wpg,
    const float* __restrict__ Abn, const float* __restrict__ Bbn,
    unsigned short* __restrict__ xwb, int n)
{
  __shared__ unsigned short bsh[16 * 512];       // 16 KB W2 staging
  __shared__ unsigned short act2[64 * 264];      // 33 KB intermediate (padded rows)
  int tid = threadIdx.x, wave = tid >> 6, lane = tid & 63;
  int l15 = lane & 15, lg = lane >> 4;
  int rbase = blockIdx.x * 64 + wave * 16;
  int arow = rbase + l15; if (arow > n - 1) arow = n - 1;
  const unsigned short* ap = &agg2[(size_t)arow * 256 + lg * 8];

  f32x4 acc[16];
  f32x4 z = {0.f, 0.f, 0.f, 0.f};
  #pragma unroll
  for (int ct = 0; ct < 16; ct++) acc[ct] = z;

  for (int ks = 0; ks < 8; ks++) {
    const unsigned short* src = Wp2 + (size_t)ks * 16 * 512 + wave * 16 * 128;
    short8 stg[4];
    #pragma unroll
    for (int c = 0; c < 4; c++)
      stg[c] = *(const short8*)(src + c * 512 + lane * 8);
    short8 a = *(const short8*)(ap + ks * 32);
    __syncthreads();
    #pragma unroll
    for (int c = 0; c < 4; c++)
      *(short8*)&bsh[wave * 16 * 128 + c * 512 + lane * 8] = stg[c];
    __syncthreads();
    #pragma unroll
    for (int ct = 0; ct < 16; ct++) {
      short8 b = *(const short8*)&bsh[(ct * 64 + lane) * 8];
      acc[ct] = __builtin_amdgcn_mfma_f32_16x16x32_bf16(a, b, acc[ct], 0, 0, 0);
    }
  }

  float abn[16], bbn[16];
  #pragma unroll
  for (int ct = 0; ct < 16; ct++) {
    abn[ct] = Abn[ct * 16 + l15];
    bbn[ct] = Bbn[ct * 16 + l15];
  }
  #pragma unroll
  for (int r = 0; r < 4; r++) {
    int row = rbase + lg * 4 + r;
    if (row < n) {
      int rl = wave * 16 + lg * 4 + r;
      #pragma unroll
      for (int ct = 0; ct < 16; ct++) {
        float v = eluf(acc[r < 0 ? 0 : ct][r] * abn[ct] + bbn[ct]);
        act2[rl * 264 + ct * 16 + l15] = f2bf(v);
      }
    }
  }
  __syncthreads();

  // stage 2: rows wave*16..+15, A from act2, B from Wpg (global, L1-hot)
  f32x4 acc2[4];
  #pragma unroll
  for (int ct = 0; ct < 4; ct++) acc2[ct] = z;
  const unsigned short* a2p = &act2[(wave * 16 + l15) * 264];
  #pragma unroll
  for (int ks = 0; ks < 8; ks++) {
    short8 a2 = *(const short8*)(a2p + ks * 32 + lg * 8);
    #pragma unroll
    for (int ct = 0; ct < 4; ct++) {
      short8 b = *(const short8*)&Wpg[(size_t)(ks * 4 + ct) * 512 + lane * 8];
      acc2[ct] = __builtin_amdgcn_mfma_f32_16x16x32_bf16(a2, b, acc2[ct], 0, 0, 0);
    }
  }
  #pragma unroll
  for (int r = 0; r < 4; r++) {
    int row = rbase + lg * 4 + r;
    if (row < n) {
      #pragma unroll
      for (int ct = 0; ct < 4; ct++)
        xwb[(size_t)row * 64 + ct * 16 + l15] = f2bf(acc2[ct][r]);
    }
  }
}

// ---------------- GCN gather: 8 slots, 2x unroll + BN/ELU -> fp32 hout ----------------
__global__ void k_gcn_gather(const int* __restrict__ rowptr, const int* __restrict__ deg,
                             const int* __restrict__ col, const float* __restrict__ dinv,
                             const unsigned short* __restrict__ xwb,
                             const float* __restrict__ bias,
                             const float* __restrict__ gg, const float* __restrict__ bb,
                             const float* __restrict__ mm, const float* __restrict__ vv,
                             float* __restrict__ hout, int n)
{
  int d = blockIdx.x * 4 + (threadIdx.x >> 6);
  if (d >= n) return;
  int lane = threadIdx.x & 63;
  int slot = lane >> 3, cg = (lane & 7) * 8;
  int start = rowptr[d], cnt = deg[d];
  float dinvd = rsqrtf(fmaxf((float)cnt, 1.f));

  float acc[8] = {0.f,0.f,0.f,0.f,0.f,0.f,0.f,0.f};
  int i = slot;
  for (; i + 8 < cnt; i += 16) {
    int s0 = col[start + i], s1 = col[start + i + 8];
    float n0 = dinv[s0], n1 = dinv[s1];
    short8 h0 = *(const short8*)&xwb[(size_t)s0 * 64 + cg];
    short8 h1 = *(const short8*)&xwb[(size_t)s1 * 64 + cg];
    #pragma unroll
    for (int j = 0; j < 8; j++)
      acc[j] += bf2f((unsigned short)h0[j]) * n0 + bf2f((unsigned short)h1[j]) * n1;
  }
  if (i < cnt) {
    int s0 = col[start + i];
    float n0 = dinv[s0];
    short8 h0 = *(const short8*)&xwb[(size_t)s0 * 64 + cg];
    #pragma unroll
    for (int j = 0; j < 8; j++)
      acc[j] += bf2f((unsigned short)h0[j]) * n0;
  }
  #pragma unroll
  for (int j = 0; j < 8; j++) {
    acc[j] += __shfl_xor(acc[j], 8, 64);
    acc[j] += __shfl_xor(acc[j], 16, 64);
    acc[j] += __shfl_xor(acc[j], 32, 64);
    acc[j] *= dinvd;
  }

  if (lane < 8) {
    float out[8];
    #pragma unroll
    for (int j = 0; j < 8; j++) {
      int c = cg + j;
      float r = ((acc[j] + bias[c]) - mm[c]) * rsqrtf(vv[c] + BN_EPS) * gg[c] + bb[c];
      out[j] = eluf(r);
    }
    *(float4*)&hout[(size_t)d * 64 + cg]     = make_float4(out[0], out[1], out[2], out[3]);
    *(float4*)&hout[(size_t)d * 64 + cg + 4] = make_float4(out[4], out[5], out[6], out[7]);
  }
}

// ---------------- pooling: per-wave run accumulation, rare flushes ----------------
__global__ void k_pool_partial(const float* __restrict__ hout, const int* __restrict__ batch,
                               float* __restrict__ psum, unsigned* __restrict__ pmaxu,
                               int n)
{
  int wave = threadIdx.x >> 6, lane = threadIdx.x & 63;
  int wbase = blockIdx.x * 128 + wave * 32;
  int wend = wbase + 32; if (wend > n) wend = n;
  if (wbase >= n) return;

  int g_cur = -1;
  float s = 0.f, mx = -1e30f;
  for (int node = wbase; node < wend; node++) {
    int g = batch[node];
    if (g != g_cur) {
      if (g_cur >= 0) {
        atomicAdd(&psum[g_cur * 64 + lane], s);
        atomicMax(&pmaxu[g_cur * 64 + lane], fmap(mx));
      }
      g_cur = g; s = 0.f; mx = -1e30f;
    }
    float v = hout[(size_t)node * 64 + lane];
    s += v;
    mx = fmaxf(mx, v);
  }
  if (g_cur >= 0) {
    atomicAdd(&psum[g_cur * 64 + lane], s);
    atomicMax(&pmaxu[g_cur * 64 + lane], fmap(mx));
  }
}

// ---------------- heads: one block (64 thr) per graph ----------------
__global__ void k_heads(const float* __restrict__ psum, const unsigned* __restrict__ pmaxu,
                        const int* __restrict__ batch,
                        const float* __restrict__ Wr, const float* __restrict__ br,
                        const float* __restrict__ Wh1, const float* __restrict__ bh1,
                        const float* __restrict__ Wh2, const float* __restrict__ bh2,
                        const float* __restrict__ Wh3, const float* __restrict__ bh3,
                        const float* __restrict__ Wl1, const float* __restrict__ bl1,
                        const float* __restrict__ Wl2, const float* __restrict__ bl2,
                        const float* __restrict__ We1, const float* __restrict__ be1,
                        const float* __restrict__ We2, const float* __restrict__ be2,
                        float* __restrict__ outp, int n, int xg_off)
{
  __shared__ float cat[128], xg[64], t1[32], t2[16], l1[32], e1[16];
  int g = blockIdx.x, c = threadIdx.x;  // 64 threads

  int lo = 0, hi = n;
  while (lo < hi) { int mid = (lo + hi) >> 1; if (batch[mid] < g) lo = mid + 1; else hi = mid; }
  int start = lo;
  lo = start; hi = n;
  while (lo < hi) { int mid = (lo + hi) >> 1; if (batch[mid] < g + 1) lo = mid + 1; else hi = mid; }
  int cntg = lo - start;

  float mean = psum[g * 64 + c] / fmaxf((float)cntg, 1.f);
  float mxv = (cntg > 0) ? funmap(pmaxu[g * 64 + c]) : 0.f;
  cat[c] = mean; cat[64 + c] = mxv;
  __syncthreads();
  float a = br[c];
  for (int i = 0; i < 128; i++) a += cat[i] * Wr[i * 64 + c];
  xg[c] = a;
  outp[xg_off + g * 64 + c] = a;
  __syncthreads();
  if (c < 32) {
    float u = bh1[c]; for (int i = 0; i < 64; i++) u += xg[i] * Wh1[i * 32 + c];
    t1[c] = fmaxf(u, 0.f);
    float v = bl1[c]; for (int i = 0; i < 64; i++) v += xg[i] * Wl1[i * 32 + c];
    l1[c] = fmaxf(v, 0.f);
  }
  __syncthreads();
  if (c < 16) {
    float u = bh2[c]; for (int i = 0; i < 32; i++) u += t1[i] * Wh2[i * 16 + c];
    t2[c] = fmaxf(u, 0.f);
    float v = be1[c]; for (int i = 0; i < 64; i++) v += xg[i] * We1[i * 16 + c];
    e1[c] = fmaxf(v, 0.f);
  }
  __syncthreads();
  if (c < 8) {
    float v = bl2[c]; for (int i = 0; i < 32; i++) v += l1[i] * Wl2[i * 8 + c];
    outp[64 + g * 8 + c] = v;
  }
  if (c == 0) {
    float u = bh3[0]; for (int i = 0; i < 16; i++) u += t2[i] * Wh3[i];
    outp[g] = 100.f / (1.f + expf(-u));
    float v = be2[0]; for (int i = 0; i < 16; i++) v += e1[i] * We2[i];
    outp[576 + g] = v;
  }
}

extern "C" void kernel_launch(void* const* d_in, const int* in_sizes, int n_in,
                              void* d_out, int out_size, void* d_ws, size_t ws_size,
                              hipStream_t stream)
{
  const float* x    = (const float*)d_in[0];
  const int*   ei   = (const int*)d_in[1];
  const int*   batch= (const int*)d_in[2];
  const float* W1   = (const float*)d_in[3];
  const float* as1  = (const float*)d_in[4];
  const float* ad1  = (const float*)d_in[5];
  const float* bi1  = (const float*)d_in[6];
  const float* W2   = (const float*)d_in[7];
  const float* as2  = (const float*)d_in[8];
  const float* ad2  = (const float*)d_in[9];
  const float* bi2  = (const float*)d_in[10];
  const float* bn1g = (const float*)d_in[11];
  const float* bn1b = (const float*)d_in[12];
  const float* bn1m = (const float*)d_in[13];
  const float* bn1v = (const float*)d_in[14];
  const float* bn2g = (const float*)d_in[15];
  const float* bn2b = (const float*)d_in[16];
  const float* bn2m = (const float*)d_in[17];
  const float* bn2v = (const float*)d_in[18];
  const float* bn3g = (const float*)d_in[19];
  const float* bn3b = (const float*)d_in[20];
  const float* bn3m = (const float*)d_in[21];
  const float* bn3v = (const float*)d_in[22];
  const float* Wg   = (const float*)d_in[23];
  const float* bg   = (const float*)d_in[24];
  const float* Wr   = (const float*)d_in[25];
  const float* br   = (const float*)d_in[26];
  const float* Wh1  = (const float*)d_in[27];
  const float* bh1  = (const float*)d_in[28];
  const float* Wh2  = (const float*)d_in[29];
  const float* bh2  = (const float*)d_in[30];
  const float* Wh3  = (const float*)d_in[31];
  const float* bh3  = (const float*)d_in[32];
  const float* Wl1  = (const float*)d_in[33];
  const float* bl1  = (const float*)d_in[34];
  const float* Wl2  = (const float*)d_in[35];
  const float* bl2  = (const float*)d_in[36];
  const float* We1  = (const float*)d_in[37];
  const float* be1  = (const float*)d_in[38];
  const float* We2  = (const float*)d_in[39];
  const float* be2  = (const float*)d_in[40];

  const int n  = in_sizes[2];         // 50000 nodes
  const int ne = in_sizes[1] / 2;     // 500000 edges
  const int e2 = ne + n;              // with self-loops

  float* ws = (float*)d_ws;
  size_t off = 0;
  unsigned short* bufA = (unsigned short*)(ws + off); off += (size_t)n * 128; // actA / xwb
  unsigned short* bufB = (unsigned short*)(ws + off); off += (size_t)n * 128; // agg2
  float* xa   = ws + off; off += (size_t)n * 40;
  float* es   = ws + off; off += (size_t)n * 4;
  float* ed   = ws + off; off += (size_t)n * 4;
  float* dinv = ws + off; off += (size_t)n;
  int* rowptr = (int*)(ws + off); off += (size_t)n + 1;
  int* deg    = (int*)(ws + off); off += (size_t)n;
  int* cursor = (int*)(ws + off); off += (size_t)n;   // adjacent to deg for joint memset
  int* col    = (int*)(ws + off); off += (size_t)e2;
  int* partials = (int*)(ws + off); off += 64;
  unsigned short* Wp2 = (unsigned short*)(ws + off); off += 32768;  // 65536 bf16
  unsigned short* Wpg = (unsigned short*)(ws + off); off += 8192;   // 16384 bf16
  float* Ws1  = ws + off; off += 40;
  float* Wd1  = ws + off; off += 40;
  float* WasT = ws + off; off += 2048;
  float* A1   = ws + off; off += 256;
  float* B1   = ws + off; off += 256;
  float* A2   = ws + off; off += 256;
  float* B2   = ws + off; off += 256;
  float* psum = ws + off; off += 64 * 64;
  unsigned* pmaxu = (unsigned*)(ws + off); off += 64 * 64;  // adjacent to psum

  unsigned short* actA = bufA;   // layer-1 activations [n][256]
  unsigned short* agg2 = bufB;   // layer-2 aggregate [n][256]
  unsigned short* xwb  = bufA;   // GCN xw [n][64]; actA dead after k_gat_gather

  float* outp = (float*)d_out;
  float* hout = outp + 640;            // node embeddings region
  const int xg_off = 640 + n * 64;

  const int eb   = (e2 + 255) / 256;
  const int gb1  = (n + 3) / 4;
  const int gmb  = (n + 63) / 64;
  const int nsb  = (n + SCAN_BLK - 1) / SCAN_BLK;

  // ---------- CSR build + precomputes ----------
  hipMemsetAsync(deg, 0, (size_t)2 * n * sizeof(int), stream);   // deg + cursor
  k_count<<<eb, 256, 0, stream>>>(ei, deg, ne, e2);
  k_scan1<<<nsb, SCAN_BLK, 0, stream>>>(deg, rowptr, partials, dinv, n);
  k_scan2<<<nsb, SCAN_BLK, 0, stream>>>(rowptr, partials, n);
  k_fill<<<eb, 256, 0, stream>>>(ei, rowptr, cursor, col, ne, e2);
  k_pack<<<128, 512, 0, stream>>>(W2, Wp2, 256, 16);
  k_pack<<<32, 512, 0, stream>>>(Wg, Wpg, 64, 4);
  k_prep_all<<<9, 256, 0, stream>>>(W1, as1, ad1, W2, as2, ad2,
                                    bi1, bn1g, bn1b, bn1m, bn1v,
                                    bi2, bn2g, bn2b, bn2m, bn2v,
                                    Ws1, Wd1, WasT, A1, B1, A2, B2);

  // ---------- GAT layer 1 (aggregate-first, fused softmax) ----------
  k_es1<<<(n + 255) / 256, 256, 0, stream>>>(x, Ws1, Wd1, es, ed, n);
  k_xagg<<<gb1, 256, 0, stream>>>(rowptr, deg, col, es, ed, x, xa, n);
  k_gemm_xa<<<gb1, 256, 0, stream>>>(xa, W1, A1, B1, WasT, actA, es, ed, n);

  // ---------- GAT layer 2 (aggregate-first, fused softmax) + GCN GEMM chain ---------
  k_gat_gather<<<gb1, 256, 0, stream>>>(rowptr, deg, col, es, ed, actA, agg2, n);
  k_mfma_gemm2<<<gmb, 256, 0, stream>>>(agg2, Wp2, Wpg, A2, B2, xwb, n);

  // ---------- GCN aggregate ----------
  k_gcn_gather<<<gb1, 256, 0, stream>>>(rowptr, deg, col, dinv, xwb,
                                        bg, bn3g, bn3b, bn3m, bn3v, hout, n);

  // ---------- pooling + heads ----------
  hipMemsetAsync(psum, 0, 2 * 64 * 64 * sizeof(float), stream);  // psum + pmaxu
  k_pool_partial<<<(n + 127) / 128, 256, 0, stream>>>(hout, batch, psum, pmaxu, n);
  k_heads<<<64, 64, 0, stream>>>(psum, pmaxu, batch, Wr, br,
                                 Wh1, bh1, Wh2, bh2, Wh3, bh3,
                                 Wl1, bl1, Wl2, bl2, We1, be1, We2, be2,
                                 outp, n, xg_off);
}

// Round 14
// 282.270 us; speedup vs baseline: 1.1284x; 1.0201x over previous
//
#include <hip/hip_runtime.h>
#include <math.h>

#define SCAN_BLK 1024
#define BN_EPS 1e-5f

typedef __attribute__((ext_vector_type(8))) short short8;
typedef __attribute__((ext_vector_type(4))) short short4v;
typedef __attribute__((ext_vector_type(4))) float f32x4;

__device__ __forceinline__ float eluf(float x){ return x > 0.f ? x : (expf(x) - 1.f); }
__device__ __forceinline__ unsigned short f2bf(float f){
  unsigned u = __float_as_uint(f);
  u += 0x7FFFu + ((u >> 16) & 1u);          // RNE
  return (unsigned short)(u >> 16);
}
__device__ __forceinline__ float bf2f(unsigned short s){
  return __uint_as_float(((unsigned)s) << 16);
}
__device__ __forceinline__ unsigned fmap(float f){
  unsigned b = __float_as_uint(f);
  return (b & 0x80000000u) ? ~b : (b | 0x80000000u);
}
__device__ __forceinline__ float funmap(unsigned u){
  unsigned b = (u & 0x80000000u) ? (u ^ 0x80000000u) : ~u;
  return __uint_as_float(b);
}
__device__ __forceinline__ float lrelu(float a){ return a > 0.f ? a : 0.2f * a; }

// ---------------- mega pack/prep: Wp2(128) | Wpg(32) | WasT(8) | Ws1/Wd1/BN(1) ------
__global__ void k_pack_prep(const float* __restrict__ W1, const float* __restrict__ as1,
                            const float* __restrict__ ad1,
                            const float* __restrict__ W2, const float* __restrict__ as2,
                            const float* __restrict__ ad2,
                            const float* __restrict__ Wg,
                            const float* __restrict__ bi1, const float* __restrict__ g1,
                            const float* __restrict__ b1, const float* __restrict__ m1,
                            const float* __restrict__ v1,
                            const float* __restrict__ bi2, const float* __restrict__ g2,
                            const float* __restrict__ b2, const float* __restrict__ m2,
                            const float* __restrict__ v2,
                            unsigned short* __restrict__ Wp2, unsigned short* __restrict__ Wpg,
                            float* __restrict__ Ws1, float* __restrict__ Wd1,
                            float* __restrict__ WasT,
                            float* __restrict__ A1, float* __restrict__ B1,
                            float* __restrict__ A2, float* __restrict__ B2)
{
  int b = blockIdx.x, tid = threadIdx.x;   // 512 threads
  if (b < 128) {
    int l = tid >> 3, j = tid & 7;
    int ct = b >> 3, ks = b & 7;
    int k = ks * 32 + (l >> 4) * 8 + j;
    int c = ct * 16 + (l & 15);
    Wp2[(size_t)(ks * 16 + ct) * 512 + tid] = f2bf(W2[(size_t)k * 256 + c]);
  } else if (b < 160) {
    int bb = b - 128;
    int l = tid >> 3, j = tid & 7;
    int ct = bb >> 3, ks = bb & 7;
    int k = ks * 32 + (l >> 4) * 8 + j;
    int c = ct * 16 + (l & 15);
    Wpg[(size_t)(ks * 4 + ct) * 512 + tid] = f2bf(Wg[(size_t)k * 64 + c]);
  } else if (b < 168) {
    if (tid < 256) {
      int g = (b - 160) * 256 + tid;           // 0..2047
      int half = g >= 1024, r = g & 1023;
      int i = r >> 2, h = r & 3;
      const float* a = half ? ad2 : as2;
      float s = 0.f;
      for (int c = 0; c < 64; c++) s += W2[(size_t)i * 256 + h * 64 + c] * a[h * 64 + c];
      WasT[(size_t)(half * 4 + h) * 256 + i] = s;
    }
  } else {
    if (tid < 80) {
      int half = tid / 40, r = tid % 40;
      int k = r / 4, h = r % 4;
      const float* a = half ? ad1 : as1;
      float s = 0.f;
      for (int c = 0; c < 64; c++) s += W1[k * 256 + h * 64 + c] * a[h * 64 + c];
      (half ? Wd1 : Ws1)[k * 4 + h] = s;
    }
    if (tid < 256) {
      float a = rsqrtf(v1[tid] + BN_EPS) * g1[tid];
      A1[tid] = a; B1[tid] = (bi1[tid] - m1[tid]) * a + b1[tid];
      a = rsqrtf(v2[tid] + BN_EPS) * g2[tid];
      A2[tid] = a; B2[tid] = (bi2[tid] - m2[tid]) * a + b2[tid];
    }
  }
}

// ---------------- fused: degree count (blocks < eb) | es1/ed1 (blocks >= eb) --------
__global__ void k_count_es1(const int* __restrict__ ei, int* __restrict__ deg,
                            const float* __restrict__ x,
                            const float* __restrict__ Ws1, const float* __restrict__ Wd1,
                            float* __restrict__ es, float* __restrict__ ed,
                            int ne, int e2, int n, int eb)
{
  if (blockIdx.x < eb) {
    int t = blockIdx.x * 256 + threadIdx.x;
    if (t >= e2) return;
    int dst = (t < ne) ? ei[ne + t] : t - ne;
    atomicAdd(&deg[dst], 1);
  } else {
    int t = (blockIdx.x - eb) * 256 + threadIdx.x;
    if (t >= n) return;
    float xr[10];
    #pragma unroll
    for (int k = 0; k < 10; k++) xr[k] = x[(size_t)t * 10 + k];
    float e0[4] = {0,0,0,0}, e1[4] = {0,0,0,0};
    #pragma unroll
    for (int k = 0; k < 10; k++) {
      #pragma unroll
      for (int h = 0; h < 4; h++) {
        e0[h] += xr[k] * Ws1[k * 4 + h];
        e1[h] += xr[k] * Wd1[k * 4 + h];
      }
    }
    *(float4*)&es[t * 4] = make_float4(e0[0], e0[1], e0[2], e0[3]);
    *(float4*)&ed[t * 4] = make_float4(e1[0], e1[1], e1[2], e1[3]);
  }
}

// scan + dinv fused
__global__ void k_scan1(const int* __restrict__ deg, int* __restrict__ rowptr,
                        int* __restrict__ partials, float* __restrict__ dinv, int n)
{
  __shared__ int sh[SCAN_BLK];
  int t = threadIdx.x, base = blockIdx.x * SCAN_BLK;
  int v = (base + t < n) ? deg[base + t] : 0;
  sh[t] = v;
  __syncthreads();
  for (int off = 1; off < SCAN_BLK; off <<= 1) {
    int u = 0;
    if (t >= off) u = sh[t - off];
    __syncthreads();
    if (t >= off) sh[t] += u;
    __syncthreads();
  }
  if (base + t < n) {
    rowptr[base + t] = sh[t] - v;   // exclusive
    dinv[base + t] = rsqrtf(fmaxf((float)v, 1.f));
  }
  if (t == SCAN_BLK - 1) partials[blockIdx.x] = sh[t];
}

__global__ void k_scan2(int* __restrict__ rowptr, const int* __restrict__ partials, int n)
{
  int base = blockIdx.x * SCAN_BLK;
  int add = 0;
  for (int i = 0; i < blockIdx.x; i++) add += partials[i];
  int t = threadIdx.x;
  if (base + t < n) rowptr[base + t] += add;
}

__global__ void k_fill(const int* __restrict__ ei, const int* __restrict__ rowptr,
                       int* __restrict__ cursor, int* __restrict__ col, int ne, int e2)
{
  int t = blockIdx.x * 256 + threadIdx.x;
  if (t >= e2) return;
  int src, dst;
  if (t < ne) { src = ei[t]; dst = ei[ne + t]; } else { src = dst = t - ne; }
  int pos = rowptr[dst] + atomicAdd(&cursor[dst], 1);
  col[pos] = src;
}

// ---------------- layer-1: fused online-softmax aggregate of raw x -> xa[N][4][10] ---
__global__ void k_xagg(const int* __restrict__ rowptr, const int* __restrict__ deg,
                       const int* __restrict__ col,
                       const float* __restrict__ es, const float* __restrict__ ed,
                       const float* __restrict__ x, float* __restrict__ xa, int n)
{
  int d = blockIdx.x * 4 + (threadIdx.x >> 6);
  if (d >= n) return;
  int lane = threadIdx.x & 63;
  int slot = lane >> 4, k = lane & 15;
  int start = rowptr[d], cnt = deg[d];
  bool active = (k < 10);
  float4 edv = *(const float4*)&ed[d * 4];

  float a0 = 0.f, a1 = 0.f, a2 = 0.f, a3 = 0.f;
  float s0 = 0.f, s1 = 0.f, s2 = 0.f, s3 = 0.f;
  int i = slot;
  for (; i + 4 < cnt; i += 8) {
    int e0 = start + i, e1 = start + i + 4;
    int sa = col[e0], sb = col[e1];
    float4 u0 = *(const float4*)&es[sa * 4];
    float4 u1 = *(const float4*)&es[sb * 4];
    float x0 = active ? x[(size_t)sa * 10 + k] : 0.f;
    float x1 = active ? x[(size_t)sb * 10 + k] : 0.f;
    float ex;
    ex = expf(lrelu(u0.x + edv.x)); a0 += ex * x0; s0 += ex;
    ex = expf(lrelu(u0.y + edv.y)); a1 += ex * x0; s1 += ex;
    ex = expf(lrelu(u0.z + edv.z)); a2 += ex * x0; s2 += ex;
    ex = expf(lrelu(u0.w + edv.w)); a3 += ex * x0; s3 += ex;
    ex = expf(lrelu(u1.x + edv.x)); a0 += ex * x1; s0 += ex;
    ex = expf(lrelu(u1.y + edv.y)); a1 += ex * x1; s1 += ex;
    ex = expf(lrelu(u1.z + edv.z)); a2 += ex * x1; s2 += ex;
    ex = expf(lrelu(u1.w + edv.w)); a3 += ex * x1; s3 += ex;
  }
  if (i < cnt) {
    int e0 = start + i;
    int sa = col[e0];
    float4 u0 = *(const float4*)&es[sa * 4];
    float x0 = active ? x[(size_t)sa * 10 + k] : 0.f;
    float ex;
    ex = expf(lrelu(u0.x + edv.x)); a0 += ex * x0; s0 += ex;
    ex = expf(lrelu(u0.y + edv.y)); a1 += ex * x0; s1 += ex;
    ex = expf(lrelu(u0.z + edv.z)); a2 += ex * x0; s2 += ex;
    ex = expf(lrelu(u0.w + edv.w)); a3 += ex * x0; s3 += ex;
  }
  a0 += __shfl_xor(a0, 16, 64); a0 += __shfl_xor(a0, 32, 64);
  a1 += __shfl_xor(a1, 16, 64); a1 += __shfl_xor(a1, 32, 64);
  a2 += __shfl_xor(a2, 16, 64); a2 += __shfl_xor(a2, 32, 64);
  a3 += __shfl_xor(a3, 16, 64); a3 += __shfl_xor(a3, 32, 64);
  s0 += __shfl_xor(s0, 16, 64); s0 += __shfl_xor(s0, 32, 64);
  s1 += __shfl_xor(s1, 16, 64); s1 += __shfl_xor(s1, 32, 64);
  s2 += __shfl_xor(s2, 16, 64); s2 += __shfl_xor(s2, 32, 64);
  s3 += __shfl_xor(s3, 16, 64); s3 += __shfl_xor(s3, 32, 64);

  if (slot == 0 && active) {
    float* xo = &xa[(size_t)d * 40];
    xo[k]      = a0 / (s0 + 1e-16f);
    xo[10 + k] = a1 / (s1 + 1e-16f);
    xo[20 + k] = a2 / (s2 + 1e-16f);
    xo[30 + k] = a3 / (s3 + 1e-16f);
  }
}

// ---------------- layer-1 GEMM + BN1 + ELU -> actA, with fused es2/ed2 epilogue ------
__global__ void k_gemm_xa(const float* __restrict__ xa, const float* __restrict__ W1,
                          const float* __restrict__ A1, const float* __restrict__ B1,
                          const float* __restrict__ WasT,
                          unsigned short* __restrict__ actA,
                          float* __restrict__ es, float* __restrict__ ed, int n)
{
  __shared__ float xal[160];
  __shared__ float actl[4][256];
  int tid = threadIdx.x;
  int n0 = blockIdx.x * 4;
  if (tid < 160 && (size_t)n0 * 40 + tid < (size_t)n * 40)
    xal[tid] = xa[(size_t)n0 * 40 + tid];
  __syncthreads();
  int c = tid, h = c >> 6;
  float w[10];
  #pragma unroll
  for (int k = 0; k < 10; k++) w[k] = W1[k * 256 + c];
  float a1 = A1[c], b1 = B1[c];
  #pragma unroll
  for (int m = 0; m < 4; m++) {
    int nn = n0 + m;
    if (nn >= n) break;
    float acc = 0.f;
    #pragma unroll
    for (int k = 0; k < 10; k++) acc += xal[m * 40 + h * 10 + k] * w[k];
    float v = eluf(acc * a1 + b1);
    actl[m][c] = v;
    actA[(size_t)nn * 256 + c] = f2bf(v);
  }
  __syncthreads();
  int wave = tid >> 6, lane = tid & 63;
  int nn = n0 + wave;
  if (nn < n) {
    float e[8] = {0,0,0,0,0,0,0,0};
    int c0 = lane * 4;
    #pragma unroll
    for (int j = 0; j < 4; j++) {
      float av = actl[wave][c0 + j];
      #pragma unroll
      for (int q = 0; q < 8; q++) e[q] += av * WasT[q * 256 + c0 + j];
    }
    #pragma unroll
    for (int off = 1; off < 64; off <<= 1) {
      #pragma unroll
      for (int q = 0; q < 8; q++) e[q] += __shfl_xor(e[q], off, 64);
    }
    if (lane == 0) {
      *(float4*)&es[nn * 4] = make_float4(e[0], e[1], e[2], e[3]);
      *(float4*)&ed[nn * 4] = make_float4(e[4], e[5], e[6], e[7]);
    }
  }
}

// ---------------- layer-2 gather: half-wave per dst, fused online softmax ------------
// 8 dsts/block; each 32-lane half-wave owns one dst (lane: 8 channels of 256).
// No cross-lane reduction needed; full 512B coalesced stores.
__global__ void k_gat_gather(const int* __restrict__ rowptr, const int* __restrict__ deg,
                             const int* __restrict__ col,
                             const float* __restrict__ es, const float* __restrict__ ed,
                             const unsigned short* __restrict__ act,
                             unsigned short* __restrict__ outb, int n)
{
  int hw = threadIdx.x >> 5;
  int d = blockIdx.x * 8 + hw;
  if (d >= n) return;
  int l32 = threadIdx.x & 31;
  int c8 = l32 * 8, head = l32 >> 3;
  int start = rowptr[d], cnt = deg[d];
  float edh = ed[d * 4 + head];

  float acc[8] = {0.f,0.f,0.f,0.f,0.f,0.f,0.f,0.f};
  float sex = 0.f;
  int i = 0;
  for (; i + 4 <= cnt; i += 4) {
    int e0 = start + i;
    int s0 = col[e0], s1 = col[e0 + 1], s2 = col[e0 + 2], s3 = col[e0 + 3];
    float x0 = expf(lrelu(es[s0 * 4 + head] + edh));
    float x1 = expf(lrelu(es[s1 * 4 + head] + edh));
    float x2 = expf(lrelu(es[s2 * 4 + head] + edh));
    float x3 = expf(lrelu(es[s3 * 4 + head] + edh));
    short8 h0 = *(const short8*)&act[(size_t)s0 * 256 + c8];
    short8 h1 = *(const short8*)&act[(size_t)s1 * 256 + c8];
    short8 h2 = *(const short8*)&act[(size_t)s2 * 256 + c8];
    short8 h3 = *(const short8*)&act[(size_t)s3 * 256 + c8];
    #pragma unroll
    for (int j = 0; j < 8; j++) {
      acc[j] += bf2f((unsigned short)h0[j]) * x0 + bf2f((unsigned short)h1[j]) * x1
              + bf2f((unsigned short)h2[j]) * x2 + bf2f((unsigned short)h3[j]) * x3;
    }
    sex += x0 + x1 + x2 + x3;
  }
  for (; i < cnt; i++) {
    int e0 = start + i;
    int s0 = col[e0];
    float x0 = expf(lrelu(es[s0 * 4 + head] + edh));
    short8 h0 = *(const short8*)&act[(size_t)s0 * 256 + c8];
    #pragma unroll
    for (int j = 0; j < 8; j++) acc[j] += bf2f((unsigned short)h0[j]) * x0;
    sex += x0;
  }
  float sv = 1.f / (sex + 1e-16f);
  short8 o;
  #pragma unroll
  for (int j = 0; j < 8; j++) o[j] = (short)f2bf(acc[j] * sv);
  *(short8*)&outb[(size_t)d * 256 + c8] = o;
}

// ---------------- fused double GEMM: agg2 @ W2 (+BN2+ELU) -> LDS -> @ Wg -> xwb ------
__global__ __launch_bounds__(256) void k_mfma_gemm2(
    const unsigned short* __restrict__ agg2, const unsigned short* __restrict__ Wp2,
    const unsigned short* __restrict__ Wpg,
    const float* __restrict__ Abn, const float* __restrict__ Bbn,
    unsigned short* __restrict__ xwb, int n)
{
  __shared__ unsigned short bsh[16 * 512];       // 16 KB W2 staging
  __shared__ unsigned short act2[64 * 264];      // 33 KB intermediate (padded rows)
  int tid = threadIdx.x, wave = tid >> 6, lane = tid & 63;
  int l15 = lane & 15, lg = lane >> 4;
  int rbase = blockIdx.x * 64 + wave * 16;
  int arow = rbase + l15; if (arow > n - 1) arow = n - 1;
  const unsigned short* ap = &agg2[(size_t)arow * 256 + lg * 8];

  f32x4 acc[16];
  f32x4 z = {0.f, 0.f, 0.f, 0.f};
  #pragma unroll
  for (int ct = 0; ct < 16; ct++) acc[ct] = z;

  for (int ks = 0; ks < 8; ks++) {
    const unsigned short* src = Wp2 + (size_t)ks * 16 * 512 + wave * 16 * 128;
    short8 stg[4];
    #pragma unroll
    for (int c = 0; c < 4; c++)
      stg[c] = *(const short8*)(src + c * 512 + lane * 8);
    short8 a = *(const short8*)(ap + ks * 32);
    __syncthreads();
    #pragma unroll
    for (int c = 0; c < 4; c++)
      *(short8*)&bsh[wave * 16 * 128 + c * 512 + lane * 8] = stg[c];
    __syncthreads();
    #pragma unroll
    for (int ct = 0; ct < 16; ct++) {
      short8 b = *(const short8*)&bsh[(ct * 64 + lane) * 8];
      acc[ct] = __builtin_amdgcn_mfma_f32_16x16x32_bf16(a, b, acc[ct], 0, 0, 0);
    }
  }

  float abn[16], bbn[16];
  #pragma unroll
  for (int ct = 0; ct < 16; ct++) {
    abn[ct] = Abn[ct * 16 + l15];
    bbn[ct] = Bbn[ct * 16 + l15];
  }
  #pragma unroll
  for (int r = 0; r < 4; r++) {
    int row = rbase + lg * 4 + r;
    if (row < n) {
      int rl = wave * 16 + lg * 4 + r;
      #pragma unroll
      for (int ct = 0; ct < 16; ct++) {
        float v = eluf(acc[ct][r] * abn[ct] + bbn[ct]);
        act2[rl * 264 + ct * 16 + l15] = f2bf(v);
      }
    }
  }
  __syncthreads();

  f32x4 acc2[4];
  #pragma unroll
  for (int ct = 0; ct < 4; ct++) acc2[ct] = z;
  const unsigned short* a2p = &act2[(wave * 16 + l15) * 264];
  #pragma unroll
  for (int ks = 0; ks < 8; ks++) {
    short8 a2 = *(const short8*)(a2p + ks * 32 + lg * 8);
    #pragma unroll
    for (int ct = 0; ct < 4; ct++) {
      short8 b = *(const short8*)&Wpg[(size_t)(ks * 4 + ct) * 512 + lane * 8];
      acc2[ct] = __builtin_amdgcn_mfma_f32_16x16x32_bf16(a2, b, acc2[ct], 0, 0, 0);
    }
  }
  #pragma unroll
  for (int r = 0; r < 4; r++) {
    int row = rbase + lg * 4 + r;
    if (row < n) {
      #pragma unroll
      for (int ct = 0; ct < 4; ct++)
        xwb[(size_t)row * 64 + ct * 16 + l15] = f2bf(acc2[ct][r]);
    }
  }
}

// ---------------- GCN gather: 8 slots, 2x unroll + BN/ELU -> fp32 hout ----------------
__global__ void k_gcn_gather(const int* __restrict__ rowptr, const int* __restrict__ deg,
                             const int* __restrict__ col, const float* __restrict__ dinv,
                             const unsigned short* __restrict__ xwb,
                             const float* __restrict__ bias,
                             const float* __restrict__ gg, const float* __restrict__ bb,
                             const float* __restrict__ mm, const float* __restrict__ vv,
                             float* __restrict__ hout, int n)
{
  int d = blockIdx.x * 4 + (threadIdx.x >> 6);
  if (d >= n) return;
  int lane = threadIdx.x & 63;
  int slot = lane >> 3, cg = (lane & 7) * 8;
  int start = rowptr[d], cnt = deg[d];
  float dinvd = rsqrtf(fmaxf((float)cnt, 1.f));

  float acc[8] = {0.f,0.f,0.f,0.f,0.f,0.f,0.f,0.f};
  int i = slot;
  for (; i + 8 < cnt; i += 16) {
    int s0 = col[start + i], s1 = col[start + i + 8];
    float n0 = dinv[s0], n1 = dinv[s1];
    short8 h0 = *(const short8*)&xwb[(size_t)s0 * 64 + cg];
    short8 h1 = *(const short8*)&xwb[(size_t)s1 * 64 + cg];
    #pragma unroll
    for (int j = 0; j < 8; j++)
      acc[j] += bf2f((unsigned short)h0[j]) * n0 + bf2f((unsigned short)h1[j]) * n1;
  }
  if (i < cnt) {
    int s0 = col[start + i];
    float n0 = dinv[s0];
    short8 h0 = *(const short8*)&xwb[(size_t)s0 * 64 + cg];
    #pragma unroll
    for (int j = 0; j < 8; j++)
      acc[j] += bf2f((unsigned short)h0[j]) * n0;
  }
  #pragma unroll
  for (int j = 0; j < 8; j++) {
    acc[j] += __shfl_xor(acc[j], 8, 64);
    acc[j] += __shfl_xor(acc[j], 16, 64);
    acc[j] += __shfl_xor(acc[j], 32, 64);
    acc[j] *= dinvd;
  }

  if (lane < 8) {
    float out[8];
    #pragma unroll
    for (int j = 0; j < 8; j++) {
      int c = cg + j;
      float r = ((acc[j] + bias[c]) - mm[c]) * rsqrtf(vv[c] + BN_EPS) * gg[c] + bb[c];
      out[j] = eluf(r);
    }
    *(float4*)&hout[(size_t)d * 64 + cg]     = make_float4(out[0], out[1], out[2], out[3]);
    *(float4*)&hout[(size_t)d * 64 + cg + 4] = make_float4(out[4], out[5], out[6], out[7]);
  }
}

// ---------------- pooling: per-wave run accumulation, rare flushes ----------------
__global__ void k_pool_partial(const float* __restrict__ hout, const int* __restrict__ batch,
                               float* __restrict__ psum, unsigned* __restrict__ pmaxu,
                               int n)
{
  int wave = threadIdx.x >> 6, lane = threadIdx.x & 63;
  int wbase = blockIdx.x * 128 + wave * 32;
  int wend = wbase + 32; if (wend > n) wend = n;
  if (wbase >= n) return;

  int g_cur = -1;
  float s = 0.f, mx = -1e30f;
  for (int node = wbase; node < wend; node++) {
    int g = batch[node];
    if (g != g_cur) {
      if (g_cur >= 0) {
        atomicAdd(&psum[g_cur * 64 + lane], s);
        atomicMax(&pmaxu[g_cur * 64 + lane], fmap(mx));
      }
      g_cur = g; s = 0.f; mx = -1e30f;
    }
    float v = hout[(size_t)node * 64 + lane];
    s += v;
    mx = fmaxf(mx, v);
  }
  if (g_cur >= 0) {
    atomicAdd(&psum[g_cur * 64 + lane], s);
    atomicMax(&pmaxu[g_cur * 64 + lane], fmap(mx));
  }
}

// ---------------- heads: one block (64 thr) per graph ----------------
__global__ void k_heads(const float* __restrict__ psum, const unsigned* __restrict__ pmaxu,
                        const int* __restrict__ batch,
                        const float* __restrict__ Wr, const float* __restrict__ br,
                        const float* __restrict__ Wh1, const float* __restrict__ bh1,
                        const float* __restrict__ Wh2, const float* __restrict__ bh2,
                        const float* __restrict__ Wh3, const float* __restrict__ bh3,
                        const float* __restrict__ Wl1, const float* __restrict__ bl1,
                        const float* __restrict__ Wl2, const float* __restrict__ bl2,
                        const float* __restrict__ We1, const float* __restrict__ be1,
                        const float* __restrict__ We2, const float* __restrict__ be2,
                        float* __restrict__ outp, int n, int xg_off)
{
  __shared__ float cat[128], xg[64], t1[32], t2[16], l1[32], e1[16];
  int g = blockIdx.x, c = threadIdx.x;  // 64 threads

  int lo = 0, hi = n;
  while (lo < hi) { int mid = (lo + hi) >> 1; if (batch[mid] < g) lo = mid + 1; else hi = mid; }
  int start = lo;
  lo = start; hi = n;
  while (lo < hi) { int mid = (lo + hi) >> 1; if (batch[mid] < g + 1) lo = mid + 1; else hi = mid; }
  int cntg = lo - start;

  float mean = psum[g * 64 + c] / fmaxf((float)cntg, 1.f);
  float mxv = (cntg > 0) ? funmap(pmaxu[g * 64 + c]) : 0.f;
  cat[c] = mean; cat[64 + c] = mxv;
  __syncthreads();
  float a = br[c];
  for (int i = 0; i < 128; i++) a += cat[i] * Wr[i * 64 + c];
  xg[c] = a;
  outp[xg_off + g * 64 + c] = a;
  __syncthreads();
  if (c < 32) {
    float u = bh1[c]; for (int i = 0; i < 64; i++) u += xg[i] * Wh1[i * 32 + c];
    t1[c] = fmaxf(u, 0.f);
    float v = bl1[c]; for (int i = 0; i < 64; i++) v += xg[i] * Wl1[i * 32 + c];
    l1[c] = fmaxf(v, 0.f);
  }
  __syncthreads();
  if (c < 16) {
    float u = bh2[c]; for (int i = 0; i < 32; i++) u += t1[i] * Wh2[i * 16 + c];
    t2[c] = fmaxf(u, 0.f);
    float v = be1[c]; for (int i = 0; i < 64; i++) v += xg[i] * We1[i * 16 + c];
    e1[c] = fmaxf(v, 0.f);
  }
  __syncthreads();
  if (c < 8) {
    float v = bl2[c]; for (int i = 0; i < 32; i++) v += l1[i] * Wl2[i * 8 + c];
    outp[64 + g * 8 + c] = v;
  }
  if (c == 0) {
    float u = bh3[0]; for (int i = 0; i < 16; i++) u += t2[i] * Wh3[i];
    outp[g] = 100.f / (1.f + expf(-u));
    float v = be2[0]; for (int i = 0; i < 16; i++) v += e1[i] * We2[i];
    outp[576 + g] = v;
  }
}

extern "C" void kernel_launch(void* const* d_in, const int* in_sizes, int n_in,
                              void* d_out, int out_size, void* d_ws, size_t ws_size,
                              hipStream_t stream)
{
  const float* x    = (const float*)d_in[0];
  const int*   ei   = (const int*)d_in[1];
  const int*   batch= (const int*)d_in[2];
  const float* W1   = (const float*)d_in[3];
  const float* as1  = (const float*)d_in[4];
  const float* ad1  = (const float*)d_in[5];
  const float* bi1  = (const float*)d_in[6];
  const float* W2   = (const float*)d_in[7];
  const float* as2  = (const float*)d_in[8];
  const float* ad2  = (const float*)d_in[9];
  const float* bi2  = (const float*)d_in[10];
  const float* bn1g = (const float*)d_in[11];
  const float* bn1b = (const float*)d_in[12];
  const float* bn1m = (const float*)d_in[13];
  const float* bn1v = (const float*)d_in[14];
  const float* bn2g = (const float*)d_in[15];
  const float* bn2b = (const float*)d_in[16];
  const float* bn2m = (const float*)d_in[17];
  const float* bn2v = (const float*)d_in[18];
  const float* bn3g = (const float*)d_in[19];
  const float* bn3b = (const float*)d_in[20];
  const float* bn3m = (const float*)d_in[21];
  const float* bn3v = (const float*)d_in[22];
  const float* Wg   = (const float*)d_in[23];
  const float* bg   = (const float*)d_in[24];
  const float* Wr   = (const float*)d_in[25];
  const float* br   = (const float*)d_in[26];
  const float* Wh1  = (const float*)d_in[27];
  const float* bh1  = (const float*)d_in[28];
  const float* Wh2  = (const float*)d_in[29];
  const float* bh2  = (const float*)d_in[30];
  const float* Wh3  = (const float*)d_in[31];
  const float* bh3  = (const float*)d_in[32];
  const float* Wl1  = (const float*)d_in[33];
  const float* bl1  = (const float*)d_in[34];
  const float* Wl2  = (const float*)d_in[35];
  const float* bl2  = (const float*)d_in[36];
  const float* We1  = (const float*)d_in[37];
  const float* be1  = (const float*)d_in[38];
  const float* We2  = (const float*)d_in[39];
  const float* be2  = (const float*)d_in[40];

  const int n  = in_sizes[2];         // 50000 nodes
  const int ne = in_sizes[1] / 2;     // 500000 edges
  const int e2 = ne + n;              // with self-loops

  float* ws = (float*)d_ws;
  size_t off = 0;
  unsigned short* bufA = (unsigned short*)(ws + off); off += (size_t)n * 128; // actA / xwb
  unsigned short* bufB = (unsigned short*)(ws + off); off += (size_t)n * 128; // agg2
  float* xa   = ws + off; off += (size_t)n * 40;
  float* es   = ws + off; off += (size_t)n * 4;
  float* ed   = ws + off; off += (size_t)n * 4;
  float* dinv = ws + off; off += (size_t)n;
  int* rowptr = (int*)(ws + off); off += (size_t)n + 1;
  int* deg    = (int*)(ws + off); off += (size_t)n;
  int* cursor = (int*)(ws + off); off += (size_t)n;   // adjacent to deg for joint memset
  int* col    = (int*)(ws + off); off += (size_t)e2;
  int* partials = (int*)(ws + off); off += 64;
  unsigned short* Wp2 = (unsigned short*)(ws + off); off += 32768;  // 65536 bf16
  unsigned short* Wpg = (unsigned short*)(ws + off); off += 8192;   // 16384 bf16
  float* Ws1  = ws + off; off += 40;
  float* Wd1  = ws + off; off += 40;
  float* WasT = ws + off; off += 2048;
  float* A1   = ws + off; off += 256;
  float* B1   = ws + off; off += 256;
  float* A2   = ws + off; off += 256;
  float* B2   = ws + off; off += 256;
  float* psum = ws + off; off += 64 * 64;
  unsigned* pmaxu = (unsigned*)(ws + off); off += 64 * 64;  // adjacent to psum

  unsigned short* actA = bufA;   // layer-1 activations [n][256]
  unsigned short* agg2 = bufB;   // layer-2 aggregate [n][256]
  unsigned short* xwb  = bufA;   // GCN xw [n][64]; actA dead after k_gat_gather

  float* outp = (float*)d_out;
  float* hout = outp + 640;            // node embeddings region
  const int xg_off = 640 + n * 64;

  const int eb   = (e2 + 255) / 256;
  const int nb1  = (n + 255) / 256;
  const int gb1  = (n + 3) / 4;
  const int gb8  = (n + 7) / 8;
  const int gmb  = (n + 63) / 64;
  const int nsb  = (n + SCAN_BLK - 1) / SCAN_BLK;

  // ---------- precomputes + CSR build ----------
  hipMemsetAsync(deg, 0, (size_t)2 * n * sizeof(int), stream);   // deg + cursor
  k_pack_prep<<<169, 512, 0, stream>>>(W1, as1, ad1, W2, as2, ad2, Wg,
                                       bi1, bn1g, bn1b, bn1m, bn1v,
                                       bi2, bn2g, bn2b, bn2m, bn2v,
                                       Wp2, Wpg, Ws1, Wd1, WasT, A1, B1, A2, B2);
  k_count_es1<<<eb + nb1, 256, 0, stream>>>(ei, deg, x, Ws1, Wd1, es, ed, ne, e2, n, eb);
  k_scan1<<<nsb, SCAN_BLK, 0, stream>>>(deg, rowptr, partials, dinv, n);
  k_scan2<<<nsb, SCAN_BLK, 0, stream>>>(rowptr, partials, n);
  k_fill<<<eb, 256, 0, stream>>>(ei, rowptr, cursor, col, ne, e2);

  // ---------- GAT layer 1 (aggregate-first, fused softmax) ----------
  k_xagg<<<gb1, 256, 0, stream>>>(rowptr, deg, col, es, ed, x, xa, n);
  k_gemm_xa<<<gb1, 256, 0, stream>>>(xa, W1, A1, B1, WasT, actA, es, ed, n);

  // ---------- GAT layer 2 (aggregate-first, fused softmax) + GEMM chain ---------
  k_gat_gather<<<gb8, 256, 0, stream>>>(rowptr, deg, col, es, ed, actA, agg2, n);
  k_mfma_gemm2<<<gmb, 256, 0, stream>>>(agg2, Wp2, Wpg, A2, B2, xwb, n);

  // ---------- GCN aggregate ----------
  k_gcn_gather<<<gb1, 256, 0, stream>>>(rowptr, deg, col, dinv, xwb,
                                        bg, bn3g, bn3b, bn3m, bn3v, hout, n);

  // ---------- pooling + heads ----------
  hipMemsetAsync(psum, 0, 2 * 64 * 64 * sizeof(float), stream);  // psum + pmaxu
  k_pool_partial<<<(n + 127) / 128, 256, 0, stream>>>(hout, batch, psum, pmaxu, n);
  k_heads<<<64, 64, 0, stream>>>(psum, pmaxu, batch, Wr, br,
                                 Wh1, bh1, Wh2, bh2, Wh3, bh3,
                                 Wl1, bl1, Wl2, bl2, We1, be1, We2, be2,
                                 outp, n, xg_off);
}